// Round 1
// 569.218 us; speedup vs baseline: 1.0158x; 1.0158x over previous
//
#include <hip/hip_runtime.h>
#include <cstdint>
#include <cstddef>

#define B_ 8
#define C_ 512
#define H_ 64
#define W_ 128
#define HW_ 8192
#define K_ 19
#define N_ 8
#define P_ 1024
#define CI_ 256

typedef unsigned short u16;
typedef unsigned int u32;
typedef __attribute__((ext_vector_type(8))) short bf16x8;   // 8 bf16 (4 VGPRs)
typedef __attribute__((ext_vector_type(4))) float f32x4;    // 4 fp32 acc

__device__ __forceinline__ u16 f2bf(float f) {
  u32 u = __float_as_uint(f);
  u32 r = (u + 0x7FFFu + ((u >> 16) & 1u)) >> 16;
  return (u16)r;
}
__device__ __forceinline__ float bf2f(u16 h) {
  return __uint_as_float(((u32)h) << 16);
}

// ---------------- block reductions (256 threads = 4 waves) ----------------
__device__ __forceinline__ float blockSum256(float v, float* red4) {
#pragma unroll
  for (int o = 32; o > 0; o >>= 1) v += __shfl_down(v, o, 64);
  __syncthreads();
  if ((threadIdx.x & 63) == 0) red4[threadIdx.x >> 6] = v;
  __syncthreads();
  return red4[0] + red4[1] + red4[2] + red4[3];
}

__device__ __forceinline__ float blockMax256(float v, float* red4) {
#pragma unroll
  for (int o = 32; o > 0; o >>= 1) v = fmaxf(v, __shfl_down(v, o, 64));
  __syncthreads();
  if ((threadIdx.x & 63) == 0) red4[threadIdx.x >> 6] = v;
  __syncthreads();
  return fmaxf(fmaxf(red4[0], red4[1]), fmaxf(red4[2], red4[3]));
}

// ---------------- merged prologue: weight casts + zeroing (1 launch) ----------------
__device__ __forceinline__ void cvt4(const float* __restrict__ s, u16* __restrict__ d, int i) {
  float4 v = *(const float4*)&s[(size_t)i * 4];
  ushort4 o;
  o.x = f2bf(v.x); o.y = f2bf(v.y); o.z = f2bf(v.z); o.w = f2bf(v.w);
  *(ushort4*)&d[(size_t)i * 4] = o;
}

// regions (vec4 elements of 4): qw 128 blk | ow 128 | kw 128 | gw2 256 | camw-pad 16 | sums-zero 1 | tbuf-pad-zero 16
__global__ __launch_bounds__(256) void prep_kernel(const float* __restrict__ qw,
                                                   const float* __restrict__ ow,
                                                   const float* __restrict__ kw,
                                                   const float* __restrict__ gw2,
                                                   const float* __restrict__ camw,
                                                   u16* __restrict__ qwbf,
                                                   u16* __restrict__ owbf,
                                                   u16* __restrict__ kwbf,
                                                   u16* __restrict__ gw2bf,
                                                   u16* __restrict__ camwbf,
                                                   float* __restrict__ sums,
                                                   float* __restrict__ tpad) {
  int bid = blockIdx.x, tid = threadIdx.x;
  if (bid < 128) {
    cvt4(qw, qwbf, bid * 256 + tid);
  } else if (bid < 256) {
    cvt4(ow, owbf, (bid - 128) * 256 + tid);
  } else if (bid < 384) {
    cvt4(kw, kwbf, (bid - 256) * 256 + tid);
  } else if (bid < 640) {
    cvt4(gw2, gw2bf, (bid - 384) * 256 + tid);
  } else if (bid < 656) {
    int i = (bid - 640) * 256 + tid;  // i*4 in [0,16384); K_*C_ = 9728 (mult of 4)
    if (i * 4 < K_ * C_) {
      cvt4(camw, camwbf, i);
    } else {
      ushort4 z; z.x = 0; z.y = 0; z.z = 0; z.w = 0;
      *(ushort4*)&camwbf[(size_t)i * 4] = z;
    }
  } else if (bid == 656) {
    float4 z; z.x = 0.f; z.y = 0.f; z.z = 0.f; z.w = 0.f;
    *(float4*)&sums[tid * 4] = z;  // sums(512)+sumsq(512) contiguous
  } else {
    int i = (bid - 657) * 256 + tid;  // 16384 floats = tbuf pad rows 1216..1279
    float4 z; z.x = 0.f; z.y = 0.f; z.z = 0.f; z.w = 0.f;
    *(float4*)&tpad[(size_t)i * 4] = z;
  }
}

// ---------------- transpose x [b,c,hw] -> xt bf16 [b,hw,c] ----------------
__global__ __launch_bounds__(256) void xpose_kernel(const float* __restrict__ x,
                                                    u16* __restrict__ xt) {
  __shared__ float tile[64][65];
  int bid = blockIdx.x;
  int hw0 = (bid & 127) << 6;
  int c0 = ((bid >> 7) & 7) << 6;
  int b = bid >> 10;
  int tid = threadIdx.x;
  int r = tid >> 4;             // 0..15
  int col4 = (tid & 15) << 2;   // 0..60
  const float* xb = x + ((size_t)b * C_ + c0) * HW_ + hw0;
#pragma unroll
  for (int it = 0; it < 4; it++) {
    int rr = r + it * 16;  // c-row
    float4 v = *(const float4*)&xb[(size_t)rr * HW_ + col4];
    tile[rr][col4 + 0] = v.x;
    tile[rr][col4 + 1] = v.y;
    tile[rr][col4 + 2] = v.z;
    tile[rr][col4 + 3] = v.w;
  }
  __syncthreads();
  u16* xo = xt + ((size_t)b * HW_ + hw0) * C_ + c0;
#pragma unroll
  for (int it = 0; it < 4; it++) {
    int hwr = r + it * 16;  // hw-row
    ushort4 o;
    o.x = f2bf(tile[col4 + 0][hwr]);
    o.y = f2bf(tile[col4 + 1][hwr]);
    o.z = f2bf(tile[col4 + 2][hwr]);
    o.w = f2bf(tile[col4 + 3][hwr]);
    *(ushort4*)&xo[(size_t)hwr * C_ + col4] = o;
  }
}

// ---------------- cam via MFMA: cam[b,k,hw] = xt[b,hw,:].camw[k,:] + camb[k] ----------------
// tile M=128(hw) x N=32(k); grid (64, 8)
__global__ __launch_bounds__(256) void gemm_cam_kernel(const u16* __restrict__ A,
                                                       const u16* __restrict__ Bw,
                                                       const float* __restrict__ bias,
                                                       float* __restrict__ cam) {
  __shared__ u16 As[128 * 72];
  __shared__ u16 Bs[32 * 72];
  int b = blockIdx.y;
  int m0 = blockIdx.x * 128;
  int tid = threadIdx.x;
  int wave = tid >> 6, lane = tid & 63;
  int wm = wave * 32;
  int quad = lane >> 4, l16 = lane & 15;
  const u16* Ab = A + (size_t)b * HW_ * C_ + (size_t)m0 * C_;
  f32x4 acc[2][2] = {};
  int sr = tid >> 3;
  int sk = (tid & 7) * 8;
  for (int k0 = 0; k0 < C_; k0 += 64) {
    __syncthreads();
#pragma unroll
    for (int it = 0; it < 4; it++) {
      int r = sr + it * 32;
      *(uint4*)&As[r * 72 + sk] = *(const uint4*)&Ab[(size_t)r * C_ + k0 + sk];
    }
    { int r = tid >> 3;  // 0..31
      *(uint4*)&Bs[r * 72 + sk] = *(const uint4*)&Bw[(size_t)r * C_ + k0 + sk]; }
    __syncthreads();
#pragma unroll
    for (int kk = 0; kk < 2; kk++) {
      bf16x8 af[2], bfv[2];
#pragma unroll
      for (int t = 0; t < 2; t++) {
        af[t] = *(const bf16x8*)&As[(wm + t * 16 + l16) * 72 + kk * 32 + quad * 8];
        bfv[t] = *(const bf16x8*)&Bs[(t * 16 + l16) * 72 + kk * 32 + quad * 8];
      }
#pragma unroll
      for (int tm = 0; tm < 2; tm++)
#pragma unroll
        for (int tn = 0; tn < 2; tn++)
          acc[tm][tn] = __builtin_amdgcn_mfma_f32_16x16x32_bf16(af[tm], bfv[tn], acc[tm][tn], 0, 0, 0);
    }
  }
  float* C = cam + (size_t)b * K_ * HW_;
#pragma unroll
  for (int tm = 0; tm < 2; tm++) {
    int mm = m0 + wm + tm * 16 + quad * 4;
#pragma unroll
    for (int tn = 0; tn < 2; tn++) {
      int nn = tn * 16 + l16;
      if (nn < K_) {
        float bv = bias[nn];
        f32x4 v = acc[tm][tn];
        v[0] += bv; v[1] += bv; v[2] += bv; v[3] += bv;
        *(f32x4*)&C[(size_t)nn * HW_ + mm] = v;
      }
    }
  }
}

// ---------------- fused cls+softmax: bconf + pconf from cam patch ----------------
__global__ __launch_bounds__(256) void softcls_kernel(const float* __restrict__ cam,
                                                      float* __restrict__ bconf,
                                                      float* __restrict__ pconf) {
  __shared__ float red4[4];
  int bid = blockIdx.x;
  int k = bid % 19;
  int n = (bid / 19) & 7;
  int b = bid / 152;
  int bh = n >> 2, bw = n & 3;
  const float* base = cam + ((size_t)b * K_ + k) * HW_ + (bh * 32) * W_ + bw * 32;
  float v[4];
  float s = 0.f, mx = -1e30f;
#pragma unroll
  for (int j = 0; j < 4; j++) {
    int p = threadIdx.x + j * 256;
    v[j] = base[(p >> 5) * W_ + (p & 31)];
    s += v[j];
    mx = fmaxf(mx, v[j]);
  }
  float tot = blockSum256(s, red4);
  if (threadIdx.x == 0) {
    float m = tot * (1.f / 1024.f);
    bconf[bid] = 1.f / (1.f + __expf(-m));
  }
  mx = blockMax256(mx, red4);
  float e[4];
  float se = 0.f;
#pragma unroll
  for (int j = 0; j < 4; j++) { e[j] = __expf(v[j] - mx); se += e[j]; }
  se = blockSum256(se, red4);
  float inv = 1.f / se;
  float* outp = pconf + (size_t)bid * P_;
#pragma unroll
  for (int j = 0; j < 4; j++) outp[threadIdx.x + j * 256] = e[j] * inv;
}

// ---------------- local partial: sum over 256-p chunk ----------------
// grid 512: pq = bid&3, half=(bid>>2)&1, n=(bid>>3)&7, b=bid>>6
// pconf LDS reads vectorized to b128 broadcasts (4x fewer LDS instrs)
__global__ __launch_bounds__(256) void local_part_kernel(const u16* __restrict__ xt,
                                                         const float* __restrict__ pconf,
                                                         float* __restrict__ part) {
  __shared__ __align__(16) float pcl[19 * 256];
  int bid = blockIdx.x;
  int pq = bid & 3;
  int half = (bid >> 2) & 1;
  int n = (bid >> 3) & 7;
  int b = bid >> 6;
  int tid = threadIdx.x;
  int c = half * 256 + tid;
  int bh = n >> 2, bw = n & 3;
  const float* pcb = pconf + (size_t)((b * N_ + n) * K_) * P_ + pq * 256;
  for (int e = tid; e < 19 * 64; e += 256) {
    int k = e >> 6, q4 = e & 63;
    *(float4*)&pcl[k * 256 + q4 * 4] = *(const float4*)&pcb[(size_t)k * P_ + q4 * 4];
  }
  __syncthreads();
  float acc[K_];
#pragma unroll
  for (int k = 0; k < K_; k++) acc[k] = 0.f;
  const u16* xb = xt + (size_t)b * HW_ * C_ + c;
  for (int pl0 = 0; pl0 < 256; pl0 += 8) {
    float xv[8];
#pragma unroll
    for (int g = 0; g < 2; g++) {
      int p = pq * 256 + pl0 + g * 4;
      int hw = (bh * 32 + (p >> 5)) * W_ + bw * 32 + (p & 31);
      const u16* xr = xb + (size_t)hw * C_;
#pragma unroll
      for (int j = 0; j < 4; j++) xv[g * 4 + j] = bf2f(xr[(size_t)j * C_]);
    }
#pragma unroll
    for (int k = 0; k < K_; k++) {
      float4 p0 = *(const float4*)&pcl[k * 256 + pl0];
      float4 p1 = *(const float4*)&pcl[k * 256 + pl0 + 4];
      acc[k] += p0.x * xv[0] + p0.y * xv[1] + p0.z * xv[2] + p0.w * xv[3]
              + p1.x * xv[4] + p1.y * xv[5] + p1.z * xv[6] + p1.w * xv[7];
    }
  }
  int row = (b * N_ + n) * K_;
  float* pp = part + ((size_t)pq * 1216 + row) * C_ + c;
#pragma unroll
  for (int k = 0; k < K_; k++) pp[(size_t)k * C_] = acc[k];
}

// ---------------- fused: local reduce (4 pq partials * bconf) + gcn conv + prelu -> bf16 ----------------
// grid 304: half=bid&1, k=(bid>>1)%19, b=(bid>>1)/19
__global__ __launch_bounds__(256) void t_kernel(const float* __restrict__ part,
                                                const float* __restrict__ bconf,
                                                const float* __restrict__ gw1,
                                                const float* __restrict__ ga,
                                                u16* __restrict__ tbuf) {
  __shared__ float gw1l[64];
  __shared__ float gal[8];
  __shared__ float bcl[8];
  int tid = threadIdx.x;
  int bid = blockIdx.x;
  int half = bid & 1;
  int rem = bid >> 1;
  int k = rem % 19;
  int b = rem / 19;
  if (tid < 64) gw1l[tid] = gw1[tid];
  if (tid < 8) {
    gal[tid] = ga[tid];
    bcl[tid] = bconf[(size_t)(b * 8 + tid) * 19 + k];
  }
  __syncthreads();
  int c = half * 256 + tid;
  float lm[8];
#pragma unroll
  for (int m = 0; m < 8; m++) {
    size_t off = ((size_t)(b * N_ + m) * K_ + k) * C_ + c;
    lm[m] = (part[off] + part[off + (size_t)1216 * 512] +
             part[off + (size_t)2 * 1216 * 512] + part[off + (size_t)3 * 1216 * 512]) * bcl[m];
  }
#pragma unroll
  for (int n = 0; n < 8; n++) {
    float v = lm[n];
#pragma unroll
    for (int m = 0; m < 8; m++) v += gw1l[n * 8 + m] * lm[m];
    float t = fmaxf(v, 0.f) + gal[n] * fminf(v, 0.f);
    tbuf[((size_t)((b * N_ + n) * K_ + k)) * C_ + c] = f2bf(t);
  }
}

// ---------------- small GEMM (M=1280 padded): C = A.Bw^T (+bias), dual fp32/bf16 out --------
template <int KDIM, int NDIM, bool BIAS>
__global__ __launch_bounds__(256) void gemm_small_kernel(const u16* __restrict__ A,
                                                         const u16* __restrict__ Bw,
                                                         const float* __restrict__ bias,
                                                         float* __restrict__ f32out,
                                                         u16* __restrict__ bf16out) {
  __shared__ u16 As[128 * 72];
  __shared__ u16 Bs[128 * 72];
  constexpr int NT = NDIM / 128;
  int m0 = (blockIdx.x / NT) * 128;
  int n0 = (blockIdx.x % NT) * 128;
  int tid = threadIdx.x;
  int wave = tid >> 6, lane = tid & 63;
  int wm = (wave >> 1) * 64, wn = (wave & 1) * 64;
  int quad = lane >> 4, l16 = lane & 15;
  const u16* Ab = A + (size_t)m0 * KDIM;
  const u16* Bb = Bw + (size_t)n0 * KDIM;
  f32x4 acc[4][4] = {};
  int sr = tid >> 3;
  int sk = (tid & 7) * 8;
  for (int k0 = 0; k0 < KDIM; k0 += 64) {
    __syncthreads();
#pragma unroll
    for (int it = 0; it < 4; it++) {
      int r = sr + it * 32;
      *(uint4*)&As[r * 72 + sk] = *(const uint4*)&Ab[(size_t)r * KDIM + k0 + sk];
      *(uint4*)&Bs[r * 72 + sk] = *(const uint4*)&Bb[(size_t)r * KDIM + k0 + sk];
    }
    __syncthreads();
#pragma unroll
    for (int kk = 0; kk < 2; kk++) {
      bf16x8 af[4], bfv[4];
#pragma unroll
      for (int t = 0; t < 4; t++) {
        af[t] = *(const bf16x8*)&As[(wm + t * 16 + l16) * 72 + kk * 32 + quad * 8];
        bfv[t] = *(const bf16x8*)&Bs[(wn + t * 16 + l16) * 72 + kk * 32 + quad * 8];
      }
#pragma unroll
      for (int tm = 0; tm < 4; tm++)
#pragma unroll
        for (int tn = 0; tn < 4; tn++)
          acc[tm][tn] = __builtin_amdgcn_mfma_f32_16x16x32_bf16(af[tm], bfv[tn], acc[tm][tn], 0, 0, 0);
    }
  }
  float bv[4];
#pragma unroll
  for (int tn = 0; tn < 4; tn++)
    bv[tn] = BIAS ? bias[n0 + wn + tn * 16 + l16] : 0.f;
#pragma unroll
  for (int tm = 0; tm < 4; tm++) {
    int mm = m0 + wm + tm * 16 + quad * 4;
#pragma unroll
    for (int tn = 0; tn < 4; tn++) {
      int nn = n0 + wn + tn * 16 + l16;
#pragma unroll
      for (int reg = 0; reg < 4; reg++) {
        float v = acc[tm][tn][reg] + bv[tn];
        if (f32out) f32out[(size_t)(mm + reg) * NDIM + nn] = v;
        if (bf16out) bf16out[(size_t)(mm + reg) * NDIM + nn] = f2bf(v);
      }
    }
  }
}

// ---------------- 6: glob + val ----------------
__global__ __launch_bounds__(256) void glob_val_kernel(const float* __restrict__ locl2,
                                                       const float* __restrict__ fw,
                                                       const float* __restrict__ fb,
                                                       const float* __restrict__ ra,
                                                       const float* __restrict__ vw,
                                                       const float* __restrict__ vb,
                                                       float* __restrict__ valo) {
  __shared__ __align__(16) float gl[512];
  int bid = blockIdx.x;
  int k = bid % 19;
  int b = bid / 19;
  int tid = threadIdx.x;
  float fwr[8];
#pragma unroll
  for (int m = 0; m < 8; m++) fwr[m] = fw[m];
  float fbv = fb[0], rav = ra[0];
  const float* lb = locl2 + ((size_t)(b * N_) * K_ + k) * C_;
  for (int c = tid; c < C_; c += 256) {
    float v = fbv;
#pragma unroll
    for (int m = 0; m < 8; m++) v += fwr[m] * lb[(size_t)m * K_ * C_ + c];
    gl[c] = fmaxf(v, 0.f) + rav * fminf(v, 0.f);
  }
  __syncthreads();
  int i = tid;
  const float* wr = vw + (size_t)i * C_;
  float s = vb[i];
  for (int c4 = 0; c4 < C_; c4 += 4) {
    float4 wv = *(const float4*)&wr[c4];
    float4 tv = *(const float4*)&gl[c4];
    s += wv.x * tv.x + wv.y * tv.y + wv.z * tv.z + wv.w * tv.w;
  }
  valo[(size_t)bid * CI_ + i] = s;
}

// ---------------- big MFMA GEMM (per-batch 8192 rows) ----------------
// XCD-aware swizzle: the NT blocks sharing an A row-panel are placed on the SAME XCD
// (same bid%8), 8 dispatch slots apart -> A panel re-reads hit that XCD's L2.
// TRANS_OUT: write fp32 C[b][n][m]; else C[b][m][n] (bf16 if OUTBF16). BNSTAT: per-channel sum/sumsq.
template <int KDIM, int NDIM, bool TRANS_OUT, bool BIAS, bool OUTBF16, bool BNSTAT>
__global__ __launch_bounds__(256) void gemm_big_kernel(const u16* __restrict__ A,
                                                       const u16* __restrict__ Bw,
                                                       const float* __restrict__ bias,
                                                       void* __restrict__ Cout,
                                                       float* __restrict__ sums,
                                                       float* __restrict__ sumsq) {
  __shared__ u16 As[128 * 72];
  __shared__ u16 Bs[128 * 72];
  constexpr int NT = NDIM / 128;
  int b = blockIdx.y;
  // swizzled decomposition (requires gridDim.x % 8 == 0 and (gridDim.x/NT) % 8 == 0)
  int d = blockIdx.x;
  int xcd = d & 7;
  int j = d >> 3;
  int m0 = (xcd + 8 * (j / NT)) * 128;
  int n0 = (j % NT) * 128;
  int tid = threadIdx.x;
  int wave = tid >> 6, lane = tid & 63;
  int wm = (wave >> 1) * 64, wn = (wave & 1) * 64;
  int quad = lane >> 4, l16 = lane & 15;
  const u16* Ab = A + (size_t)b * 8192 * KDIM + (size_t)m0 * KDIM;
  const u16* Bb = Bw + (size_t)n0 * KDIM;
  f32x4 acc[4][4] = {};
  int sr = tid >> 3;
  int sk = (tid & 7) * 8;
  for (int k0 = 0; k0 < KDIM; k0 += 64) {
    __syncthreads();
#pragma unroll
    for (int it = 0; it < 4; it++) {
      int r = sr + it * 32;
      *(uint4*)&As[r * 72 + sk] = *(const uint4*)&Ab[(size_t)r * KDIM + k0 + sk];
      *(uint4*)&Bs[r * 72 + sk] = *(const uint4*)&Bb[(size_t)r * KDIM + k0 + sk];
    }
    __syncthreads();
#pragma unroll
    for (int kk = 0; kk < 2; kk++) {
      bf16x8 af[4], bfv[4];
#pragma unroll
      for (int t = 0; t < 4; t++) {
        af[t] = *(const bf16x8*)&As[(wm + t * 16 + l16) * 72 + kk * 32 + quad * 8];
        bfv[t] = *(const bf16x8*)&Bs[(wn + t * 16 + l16) * 72 + kk * 32 + quad * 8];
      }
#pragma unroll
      for (int tm = 0; tm < 4; tm++)
#pragma unroll
        for (int tn = 0; tn < 4; tn++)
          acc[tm][tn] = __builtin_amdgcn_mfma_f32_16x16x32_bf16(af[tm], bfv[tn], acc[tm][tn], 0, 0, 0);
    }
  }
  if constexpr (!TRANS_OUT) {
    float bv[4];
#pragma unroll
    for (int tn = 0; tn < 4; tn++)
      bv[tn] = BIAS ? bias[n0 + wn + tn * 16 + l16] : 0.f;
#pragma unroll
    for (int tm = 0; tm < 4; tm++) {
      int mm = m0 + wm + tm * 16 + quad * 4;
#pragma unroll
      for (int tn = 0; tn < 4; tn++) {
        int nn = n0 + wn + tn * 16 + l16;
        if constexpr (OUTBF16) {
          u16* C = (u16*)Cout + (size_t)b * 8192 * NDIM;
#pragma unroll
          for (int reg = 0; reg < 4; reg++)
            C[(size_t)(mm + reg) * NDIM + nn] = f2bf(acc[tm][tn][reg] + bv[tn]);
        } else {
          float* C = (float*)Cout + (size_t)b * 8192 * NDIM;
#pragma unroll
          for (int reg = 0; reg < 4; reg++)
            C[(size_t)(mm + reg) * NDIM + nn] = acc[tm][tn][reg] + bv[tn];
        }
      }
    }
  } else {
    float* C = (float*)Cout + (size_t)b * NDIM * 8192;
#pragma unroll
    for (int tm = 0; tm < 4; tm++) {
      int mm = m0 + wm + tm * 16 + quad * 4;
#pragma unroll
      for (int tn = 0; tn < 4; tn++) {
        int nn = n0 + wn + tn * 16 + l16;
        *(f32x4*)&C[(size_t)nn * 8192 + mm] = acc[tm][tn];
      }
    }
    if constexpr (BNSTAT) {
#pragma unroll
      for (int tn = 0; tn < 4; tn++) {
        int nn = n0 + wn + tn * 16 + l16;
        float s = 0.f, q = 0.f;
#pragma unroll
        for (int tm = 0; tm < 4; tm++)
#pragma unroll
          for (int reg = 0; reg < 4; reg++) {
            float v = acc[tm][tn][reg];
            s += v;
            q += v * v;
          }
        s += __shfl_xor(s, 16, 64); q += __shfl_xor(q, 16, 64);
        s += __shfl_xor(s, 32, 64); q += __shfl_xor(q, 32, 64);
        if (quad == 0) {
          atomicAdd(&sums[nn], s);
          atomicAdd(&sumsq[nn], q);
        }
      }
    }
  }
}

// ---------------- attention ----------------
__global__ __launch_bounds__(256) void attn2_kernel(const u16* __restrict__ q,
                                                    const float* __restrict__ keyo,
                                                    const float* __restrict__ valo,
                                                    u16* __restrict__ obuf) {
  __shared__ float keyl[19 * 256];
  __shared__ float vall[19 * 256];
  __shared__ float aff[128 * 20];
  int bid = blockIdx.x;
  int rg = bid & 7;
  int n = (bid >> 3) & 7;
  int b = bid >> 6;
  int bh = n >> 2, bw = n & 3;
  int tid = threadIdx.x;
  const float* ksrc = keyo + (size_t)((b * 8 + n) * 19) * 256;
  for (int e = tid; e < 19 * 256; e += 256) keyl[e] = ksrc[e];
  __syncthreads();
  if (tid < 128) {
    int r = rg * 4 + (tid >> 5);
    int wc = tid & 31;
    int hw = (bh * 32 + r) * W_ + bw * 32 + wc;
    const u16* qr = q + ((size_t)b * HW_ + hw) * 256;
    float acc[19];
#pragma unroll
    for (int k = 0; k < 19; k++) acc[k] = 0.f;
    for (int i0 = 0; i0 < 256; i0 += 8) {
      uint4 v = *(const uint4*)&qr[i0];
      float f0 = __uint_as_float((v.x & 0xFFFFu) << 16);
      float f1 = __uint_as_float(v.x & 0xFFFF0000u);
      float f2 = __uint_as_float((v.y & 0xFFFFu) << 16);
      float f3 = __uint_as_float(v.y & 0xFFFF0000u);
      float f4 = __uint_as_float((v.z & 0xFFFFu) << 16);
      float f5 = __uint_as_float(v.z & 0xFFFF0000u);
      float f6 = __uint_as_float((v.w & 0xFFFFu) << 16);
      float f7 = __uint_as_float(v.w & 0xFFFF0000u);
#pragma unroll
      for (int k = 0; k < 19; k++) {
        const float* kr = &keyl[k * 256 + i0];
        acc[k] += f0 * kr[0] + f1 * kr[1] + f2 * kr[2] + f3 * kr[3] +
                  f4 * kr[4] + f5 * kr[5] + f6 * kr[6] + f7 * kr[7];
      }
    }
    float mx = -1e30f;
#pragma unroll
    for (int k = 0; k < 19; k++) mx = fmaxf(mx, acc[k]);
    float se = 0.f;
#pragma unroll
    for (int k = 0; k < 19; k++) { acc[k] = __expf(acc[k] - mx); se += acc[k]; }
    float inv = 1.f / se;
#pragma unroll
    for (int k = 0; k < 19; k++) aff[tid * 20 + k] = acc[k] * inv;
  } else {
    const float* vsrc = valo + (size_t)b * 19 * 256;
    for (int e = tid - 128; e < 19 * 256; e += 128) vall[e] = vsrc[e];
  }
  __syncthreads();
  int px = tid & 127;
  int ih = (tid >> 7) * 128;
  int r3 = rg * 4 + (px >> 5);
  int wc3 = px & 31;
  int hw3 = (bh * 32 + r3) * W_ + bw * 32 + wc3;
  float av[19];
#pragma unroll
  for (int k = 0; k < 19; k++) av[k] = aff[px * 20 + k];
  u16* ob = obuf + ((size_t)b * HW_ + hw3) * 256 + ih;
  for (int i0 = 0; i0 < 128; i0 += 16) {
    float o16[16];
#pragma unroll
    for (int j = 0; j < 16; j++) o16[j] = 0.f;
#pragma unroll
    for (int k = 0; k < 19; k++) {
      float a = av[k];
      const float* vr = &vall[k * 256 + ih + i0];
#pragma unroll
      for (int j = 0; j < 16; j++) o16[j] += a * vr[j];
    }
    uint4 w0, w1;
    w0.x = (u32)f2bf(o16[0]) | ((u32)f2bf(o16[1]) << 16);
    w0.y = (u32)f2bf(o16[2]) | ((u32)f2bf(o16[3]) << 16);
    w0.z = (u32)f2bf(o16[4]) | ((u32)f2bf(o16[5]) << 16);
    w0.w = (u32)f2bf(o16[6]) | ((u32)f2bf(o16[7]) << 16);
    w1.x = (u32)f2bf(o16[8]) | ((u32)f2bf(o16[9]) << 16);
    w1.y = (u32)f2bf(o16[10]) | ((u32)f2bf(o16[11]) << 16);
    w1.z = (u32)f2bf(o16[12]) | ((u32)f2bf(o16[13]) << 16);
    w1.w = (u32)f2bf(o16[14]) | ((u32)f2bf(o16[15]) << 16);
    *(uint4*)&ob[i0] = w0;
    *(uint4*)&ob[i0 + 8] = w1;
  }
}

__global__ __launch_bounds__(512) void bnfinal_kernel(const float* __restrict__ sums,
                                                      const float* __restrict__ sumsq,
                                                      const float* __restrict__ gamma,
                                                      const float* __restrict__ beta,
                                                      float* __restrict__ scale,
                                                      float* __restrict__ shift) {
  int c = threadIdx.x;
  const float inv_cnt = 1.f / 65536.f;
  float mu = sums[c] * inv_cnt;
  float var = sumsq[c] * inv_cnt - mu * mu;
  float iv = rsqrtf(var + 1e-5f);
  float sc = gamma[c] * iv;
  scale[c] = sc;
  shift[c] = beta[c] - mu * sc;
}

// 16 floats/thread, strided by 1024 floats within a 4096-float block window
// (window stays inside one 8192-float c-row -> c uniform per block)
__global__ __launch_bounds__(256) void final_kernel(const float* __restrict__ x,
                                                    const float* __restrict__ scale,
                                                    const float* __restrict__ shift,
                                                    const float* __restrict__ oa,
                                                    float* __restrict__ out) {
  size_t base = (size_t)blockIdx.x * 4096 + threadIdx.x * 4;
  int c = (int)((base >> 13) & 511);
  float sc = scale[c], sh = shift[c], a = oa[c];
#pragma unroll
  for (int jj = 0; jj < 4; jj++) {
    size_t idx = base + (size_t)jj * 1024;
    float4 y = *(float4*)&out[idx];
    float4 xv = *(const float4*)&x[idx];
    float4 r;
    float t;
    t = y.x * sc + sh; r.x = xv.x + fmaxf(t, 0.f) + a * fminf(t, 0.f);
    t = y.y * sc + sh; r.y = xv.y + fmaxf(t, 0.f) + a * fminf(t, 0.f);
    t = y.z * sc + sh; r.z = xv.z + fmaxf(t, 0.f) + a * fminf(t, 0.f);
    t = y.w * sc + sh; r.w = xv.w + fmaxf(t, 0.f) + a * fminf(t, 0.f);
    *(float4*)&out[idx] = r;
  }
}

extern "C" void kernel_launch(void* const* d_in, const int* in_sizes, int n_in,
                              void* d_out, int out_size, void* d_ws, size_t ws_size,
                              hipStream_t stream) {
  const float* x     = (const float*)d_in[0];
  const float* camw  = (const float*)d_in[1];
  const float* camb  = (const float*)d_in[2];
  const float* gw1   = (const float*)d_in[3];
  const float* ga    = (const float*)d_in[4];
  const float* gw2   = (const float*)d_in[5];
  const float* fw    = (const float*)d_in[6];
  const float* fb    = (const float*)d_in[7];
  const float* ra    = (const float*)d_in[8];
  const float* qw    = (const float*)d_in[9];
  const float* qb    = (const float*)d_in[10];
  const float* kw    = (const float*)d_in[11];
  const float* kb    = (const float*)d_in[12];
  const float* vw    = (const float*)d_in[13];
  const float* vb    = (const float*)d_in[14];
  const float* ow    = (const float*)d_in[15];
  const float* gamma = (const float*)d_in[16];
  const float* beta  = (const float*)d_in[17];
  const float* oa    = (const float*)d_in[18];
  float* out = (float*)d_out;
  float* ws = (float*)d_ws;

  // ---- workspace layout (float units) ----
  float* cam    = ws;                    // 1,245,184
  float* bconf  = cam + 1245184;         // 2,048 pad
  float* pconf  = bconf + 2048;          // 1,245,184
  float* locl   = pconf + 1245184;       // 622,592 (unused, layout kept)
  float* locl2f = locl + 622592;         // 1280*512 = 655,360
  float* keyo   = locl2f + 655360;       // 1280*256 = 327,680
  float* valo   = keyo + 327680;         // 38,912
  float* sums   = valo + 38912;          // 512
  float* sumsq  = sums + 512;            // 512
  float* scale  = sumsq + 512;           // 512
  float* shift  = scale + 512;           // 512
  u16* qwbf   = (u16*)(shift + 512);     // 131,072
  u16* owbf   = qwbf + 131072;           // 131,072
  u16* kwbf   = owbf + 131072;           // 131,072
  u16* gw2bf  = kwbf + 131072;           // 262,144
  u16* camwbf = gw2bf + 262144;          // 16,384 (32x512)
  u16* tbuf   = camwbf + 16384;          // 1280*512 = 655,360
  u16* l2bf   = tbuf + 655360;           // 1280*512 = 655,360
  u16* xt     = l2bf + 655360;           // 33,554,432 (64 MB)
  u16* obuf   = xt;                      // overlay: all xt readers precede attn2
  u16* qbuf   = xt + 33554432;           // 16,777,216 (32 MB)
  float* part = (float*)qbuf;            // overlay: 4*1216*512 = 2,490,368 f, consumed before qproj

  prep_kernel<<<673, 256, 0, stream>>>(qw, ow, kw, gw2, camw,
                                       qwbf, owbf, kwbf, gw2bf, camwbf,
                                       sums, (float*)(tbuf + 1216 * 512));
  xpose_kernel<<<8192, 256, 0, stream>>>(x, xt);
  gemm_cam_kernel<<<dim3(64, 8), 256, 0, stream>>>(xt, camwbf, camb, cam);
  softcls_kernel<<<1216, 256, 0, stream>>>(cam, bconf, pconf);
  local_part_kernel<<<512, 256, 0, stream>>>(xt, pconf, part);
  t_kernel<<<304, 256, 0, stream>>>(part, bconf, gw1, ga, tbuf);
  gemm_small_kernel<512, 512, false>
      <<<40, 256, 0, stream>>>(tbuf, gw2bf, nullptr, locl2f, l2bf);
  gemm_small_kernel<512, 256, true>
      <<<20, 256, 0, stream>>>(l2bf, kwbf, kb, keyo, nullptr);
  glob_val_kernel<<<152, 256, 0, stream>>>(locl2f, fw, fb, ra, vw, vb, valo);
  gemm_big_kernel<512, 256, false, true, true, false>
      <<<dim3(128, 8), 256, 0, stream>>>(xt, qwbf, qb, qbuf, nullptr, nullptr);
  attn2_kernel<<<512, 256, 0, stream>>>(qbuf, keyo, valo, obuf);
  gemm_big_kernel<256, 512, true, false, false, true>
      <<<dim3(256, 8), 256, 0, stream>>>(obuf, owbf, nullptr, out, sums, sumsq);
  bnfinal_kernel<<<1, 512, 0, stream>>>(sums, sumsq, gamma, beta, scale, shift);
  final_kernel<<<8192, 256, 0, stream>>>(x, scale, shift, oa, out);
}

// Round 2
// 549.301 us; speedup vs baseline: 1.0526x; 1.0363x over previous
//
#include <hip/hip_runtime.h>
#include <cstdint>
#include <cstddef>

#define B_ 8
#define C_ 512
#define H_ 64
#define W_ 128
#define HW_ 8192
#define K_ 19
#define N_ 8
#define P_ 1024
#define CI_ 256

typedef unsigned short u16;
typedef unsigned int u32;
typedef __attribute__((ext_vector_type(8))) short bf16x8;   // 8 bf16 (4 VGPRs)
typedef __attribute__((ext_vector_type(4))) float f32x4;    // 4 fp32 acc

__device__ __forceinline__ u16 f2bf(float f) {
  u32 u = __float_as_uint(f);
  u32 r = (u + 0x7FFFu + ((u >> 16) & 1u)) >> 16;
  return (u16)r;
}
__device__ __forceinline__ float bf2f(u16 h) {
  return __uint_as_float(((u32)h) << 16);
}

// async global->LDS, 16B per lane; LDS dest is wave-uniform base + lane*16
__device__ __forceinline__ void gload16(const u16* g, u16* l) {
  __builtin_amdgcn_global_load_lds(
      (const __attribute__((address_space(1))) unsigned int*)g,
      (__attribute__((address_space(3))) unsigned int*)l, 16, 0, 0);
}

// ---- swizzled tile staging: tile rows of 64 u16 (128B), chunk-XOR swizzle ----
// physical chunk (16B) within row = logical_chunk ^ (row&7). Staged via
// pre-swizzled GLOBAL source + linear LDS dest; read back with same XOR.
// stage 128 rows (row stride ld u16), k-window at column k0
__device__ __forceinline__ void stage128(const u16* __restrict__ src, size_t ld, int k0,
                                         u16* lds, int wave, int lane) {
  int rsub = lane >> 3;                       // 0..7 row within wave-instr
  int swz = ((lane & 7) ^ rsub) << 3;         // u16 offset within row (16B chunks)
#pragma unroll
  for (int i = 0; i < 4; i++) {
    int rowbase = wave * 8 + i * 32;
    gload16(src + (size_t)(rowbase + rsub) * ld + k0 + swz, lds + rowbase * 64);
  }
}
// stage 32 rows (one pass, 4 waves x 8 rows)
__device__ __forceinline__ void stage32(const u16* __restrict__ src, size_t ld, int k0,
                                        u16* lds, int wave, int lane) {
  int rsub = lane >> 3;
  int swz = ((lane & 7) ^ rsub) << 3;
  int rowbase = wave * 8;
  gload16(src + (size_t)(rowbase + rsub) * ld + k0 + swz, lds + rowbase * 64);
}
// read a bf16x8 fragment: logical col-bytes q at row, applying the XOR
__device__ __forceinline__ bf16x8 frag(const u16* lds, int row, int qbyte) {
  return *(const bf16x8*)((const char*)lds + row * 128 + (qbyte ^ ((row & 7) << 4)));
}

// ---------------- block reductions (256 threads = 4 waves) ----------------
__device__ __forceinline__ float blockSum256(float v, float* red4) {
#pragma unroll
  for (int o = 32; o > 0; o >>= 1) v += __shfl_down(v, o, 64);
  __syncthreads();
  if ((threadIdx.x & 63) == 0) red4[threadIdx.x >> 6] = v;
  __syncthreads();
  return red4[0] + red4[1] + red4[2] + red4[3];
}

__device__ __forceinline__ float blockMax256(float v, float* red4) {
#pragma unroll
  for (int o = 32; o > 0; o >>= 1) v = fmaxf(v, __shfl_down(v, o, 64));
  __syncthreads();
  if ((threadIdx.x & 63) == 0) red4[threadIdx.x >> 6] = v;
  __syncthreads();
  return fmaxf(fmaxf(red4[0], red4[1]), fmaxf(red4[2], red4[3]));
}

__device__ __forceinline__ void cvt4(const float* __restrict__ s, u16* __restrict__ d, int i) {
  float4 v = *(const float4*)&s[(size_t)i * 4];
  ushort4 o;
  o.x = f2bf(v.x); o.y = f2bf(v.y); o.z = f2bf(v.z); o.w = f2bf(v.w);
  *(ushort4*)&d[(size_t)i * 4] = o;
}

// ---------------- fused transpose + prologue (weight casts / zeroing) ----------------
// blocks 0..8191: transpose x [b,c,hw] -> xt bf16 [b,hw,c]; blocks 8192..8864: prep
__global__ __launch_bounds__(256) void xpose_prep_kernel(const float* __restrict__ x,
                                                         u16* __restrict__ xt,
                                                         const float* __restrict__ qw,
                                                         const float* __restrict__ ow,
                                                         const float* __restrict__ kw,
                                                         const float* __restrict__ gw2,
                                                         const float* __restrict__ camw,
                                                         u16* __restrict__ qwbf,
                                                         u16* __restrict__ owbf,
                                                         u16* __restrict__ kwbf,
                                                         u16* __restrict__ gw2bf,
                                                         u16* __restrict__ camwbf,
                                                         float* __restrict__ sums,
                                                         float* __restrict__ tpad) {
  __shared__ float tile[64][65];
  int bid = blockIdx.x;
  int tid = threadIdx.x;
  if (bid >= 8192) {
    int pb = bid - 8192;
    if (pb < 128) {
      cvt4(qw, qwbf, pb * 256 + tid);
    } else if (pb < 256) {
      cvt4(ow, owbf, (pb - 128) * 256 + tid);
    } else if (pb < 384) {
      cvt4(kw, kwbf, (pb - 256) * 256 + tid);
    } else if (pb < 640) {
      cvt4(gw2, gw2bf, (pb - 384) * 256 + tid);
    } else if (pb < 656) {
      int i = (pb - 640) * 256 + tid;
      if (i * 4 < K_ * C_) {
        cvt4(camw, camwbf, i);
      } else {
        ushort4 z; z.x = 0; z.y = 0; z.z = 0; z.w = 0;
        *(ushort4*)&camwbf[(size_t)i * 4] = z;
      }
    } else if (pb == 656) {
      float4 z; z.x = 0.f; z.y = 0.f; z.z = 0.f; z.w = 0.f;
      *(float4*)&sums[tid * 4] = z;  // sums(512)+sumsq(512) contiguous
    } else {
      int i = (pb - 657) * 256 + tid;
      float4 z; z.x = 0.f; z.y = 0.f; z.z = 0.f; z.w = 0.f;
      *(float4*)&tpad[(size_t)i * 4] = z;
    }
    return;
  }
  int hw0 = (bid & 127) << 6;
  int c0 = ((bid >> 7) & 7) << 6;
  int b = bid >> 10;
  int r = tid >> 4;             // 0..15
  int col4 = (tid & 15) << 2;   // 0..60
  const float* xb = x + ((size_t)b * C_ + c0) * HW_ + hw0;
#pragma unroll
  for (int it = 0; it < 4; it++) {
    int rr = r + it * 16;  // c-row
    float4 v = *(const float4*)&xb[(size_t)rr * HW_ + col4];
    tile[rr][col4 + 0] = v.x;
    tile[rr][col4 + 1] = v.y;
    tile[rr][col4 + 2] = v.z;
    tile[rr][col4 + 3] = v.w;
  }
  __syncthreads();
  u16* xo = xt + ((size_t)b * HW_ + hw0) * C_ + c0;
#pragma unroll
  for (int it = 0; it < 4; it++) {
    int hwr = r + it * 16;  // hw-row
    ushort4 o;
    o.x = f2bf(tile[col4 + 0][hwr]);
    o.y = f2bf(tile[col4 + 1][hwr]);
    o.z = f2bf(tile[col4 + 2][hwr]);
    o.w = f2bf(tile[col4 + 3][hwr]);
    *(ushort4*)&xo[(size_t)hwr * C_ + col4] = o;
  }
}

// ---------------- cam via MFMA: cam[b,k,hw] = xt[b,hw,:].camw[k,:] + camb[k] ----------------
// tile M=128(hw) x N=32(k); grid (64, 8)
__global__ __launch_bounds__(256) void gemm_cam_kernel(const u16* __restrict__ A,
                                                       const u16* __restrict__ Bw,
                                                       const float* __restrict__ bias,
                                                       float* __restrict__ cam) {
  __shared__ __align__(16) u16 As[128 * 64];
  __shared__ __align__(16) u16 Bs[32 * 64];
  int b = blockIdx.y;
  int m0 = blockIdx.x * 128;
  int tid = threadIdx.x;
  int wave = tid >> 6, lane = tid & 63;
  int wm = wave * 32;
  int quad = lane >> 4, l16 = lane & 15;
  const u16* Ab = A + (size_t)b * HW_ * C_ + (size_t)m0 * C_;
  f32x4 acc[2][2] = {};
  for (int k0 = 0; k0 < C_; k0 += 64) {
    __syncthreads();
    stage128(Ab, C_, k0, As, wave, lane);
    stage32(Bw, C_, k0, Bs, wave, lane);
    __syncthreads();
#pragma unroll
    for (int kk = 0; kk < 2; kk++) {
      int qb_ = kk * 64 + quad * 16;
      bf16x8 af[2], bfv[2];
#pragma unroll
      for (int t = 0; t < 2; t++) {
        af[t] = frag(As, wm + t * 16 + l16, qb_);
        bfv[t] = frag(Bs, t * 16 + l16, qb_);
      }
#pragma unroll
      for (int tm = 0; tm < 2; tm++)
#pragma unroll
        for (int tn = 0; tn < 2; tn++)
          acc[tm][tn] = __builtin_amdgcn_mfma_f32_16x16x32_bf16(af[tm], bfv[tn], acc[tm][tn], 0, 0, 0);
    }
  }
  float* C = cam + (size_t)b * K_ * HW_;
#pragma unroll
  for (int tm = 0; tm < 2; tm++) {
    int mm = m0 + wm + tm * 16 + quad * 4;
#pragma unroll
    for (int tn = 0; tn < 2; tn++) {
      int nn = tn * 16 + l16;
      if (nn < K_) {
        float bv = bias[nn];
        f32x4 v = acc[tm][tn];
        v[0] += bv; v[1] += bv; v[2] += bv; v[3] += bv;
        *(f32x4*)&C[(size_t)nn * HW_ + mm] = v;
      }
    }
  }
}

// ---------------- fused cls+softmax: bconf + pconf from cam patch ----------------
__global__ __launch_bounds__(256) void softcls_kernel(const float* __restrict__ cam,
                                                      float* __restrict__ bconf,
                                                      float* __restrict__ pconf) {
  __shared__ float red4[4];
  int bid = blockIdx.x;
  int k = bid % 19;
  int n = (bid / 19) & 7;
  int b = bid / 152;
  int bh = n >> 2, bw = n & 3;
  const float* base = cam + ((size_t)b * K_ + k) * HW_ + (bh * 32) * W_ + bw * 32;
  float v[4];
  float s = 0.f, mx = -1e30f;
#pragma unroll
  for (int j = 0; j < 4; j++) {
    int p = threadIdx.x + j * 256;
    v[j] = base[(p >> 5) * W_ + (p & 31)];
    s += v[j];
    mx = fmaxf(mx, v[j]);
  }
  float tot = blockSum256(s, red4);
  if (threadIdx.x == 0) {
    float m = tot * (1.f / 1024.f);
    bconf[bid] = 1.f / (1.f + __expf(-m));
  }
  mx = blockMax256(mx, red4);
  float e[4];
  float se = 0.f;
#pragma unroll
  for (int j = 0; j < 4; j++) { e[j] = __expf(v[j] - mx); se += e[j]; }
  se = blockSum256(se, red4);
  float inv = 1.f / se;
  float* outp = pconf + (size_t)bid * P_;
#pragma unroll
  for (int j = 0; j < 4; j++) outp[threadIdx.x + j * 256] = e[j] * inv;
}

// ---------------- local partial: sum over 256-p chunk ----------------
__global__ __launch_bounds__(256) void local_part_kernel(const u16* __restrict__ xt,
                                                         const float* __restrict__ pconf,
                                                         float* __restrict__ part) {
  __shared__ __align__(16) float pcl[19 * 256];
  int bid = blockIdx.x;
  int pq = bid & 3;
  int half = (bid >> 2) & 1;
  int n = (bid >> 3) & 7;
  int b = bid >> 6;
  int tid = threadIdx.x;
  int c = half * 256 + tid;
  int bh = n >> 2, bw = n & 3;
  const float* pcb = pconf + (size_t)((b * N_ + n) * K_) * P_ + pq * 256;
  for (int e = tid; e < 19 * 64; e += 256) {
    int k = e >> 6, q4 = e & 63;
    *(float4*)&pcl[k * 256 + q4 * 4] = *(const float4*)&pcb[(size_t)k * P_ + q4 * 4];
  }
  __syncthreads();
  float acc[K_];
#pragma unroll
  for (int k = 0; k < K_; k++) acc[k] = 0.f;
  const u16* xb = xt + (size_t)b * HW_ * C_ + c;
  for (int pl0 = 0; pl0 < 256; pl0 += 8) {
    float xv[8];
#pragma unroll
    for (int g = 0; g < 2; g++) {
      int p = pq * 256 + pl0 + g * 4;
      int hw = (bh * 32 + (p >> 5)) * W_ + bw * 32 + (p & 31);
      const u16* xr = xb + (size_t)hw * C_;
#pragma unroll
      for (int j = 0; j < 4; j++) xv[g * 4 + j] = bf2f(xr[(size_t)j * C_]);
    }
#pragma unroll
    for (int k = 0; k < K_; k++) {
      float4 p0 = *(const float4*)&pcl[k * 256 + pl0];
      float4 p1 = *(const float4*)&pcl[k * 256 + pl0 + 4];
      acc[k] += p0.x * xv[0] + p0.y * xv[1] + p0.z * xv[2] + p0.w * xv[3]
              + p1.x * xv[4] + p1.y * xv[5] + p1.z * xv[6] + p1.w * xv[7];
    }
  }
  int row = (b * N_ + n) * K_;
  float* pp = part + ((size_t)pq * 1216 + row) * C_ + c;
#pragma unroll
  for (int k = 0; k < K_; k++) pp[(size_t)k * C_] = acc[k];
}

// ---------------- fused: local reduce + gcn conv + prelu -> bf16 ----------------
__global__ __launch_bounds__(256) void t_kernel(const float* __restrict__ part,
                                                const float* __restrict__ bconf,
                                                const float* __restrict__ gw1,
                                                const float* __restrict__ ga,
                                                u16* __restrict__ tbuf) {
  __shared__ float gw1l[64];
  __shared__ float gal[8];
  __shared__ float bcl[8];
  int tid = threadIdx.x;
  int bid = blockIdx.x;
  int half = bid & 1;
  int rem = bid >> 1;
  int k = rem % 19;
  int b = rem / 19;
  if (tid < 64) gw1l[tid] = gw1[tid];
  if (tid < 8) {
    gal[tid] = ga[tid];
    bcl[tid] = bconf[(size_t)(b * 8 + tid) * 19 + k];
  }
  __syncthreads();
  int c = half * 256 + tid;
  float lm[8];
#pragma unroll
  for (int m = 0; m < 8; m++) {
    size_t off = ((size_t)(b * N_ + m) * K_ + k) * C_ + c;
    lm[m] = (part[off] + part[off + (size_t)1216 * 512] +
             part[off + (size_t)2 * 1216 * 512] + part[off + (size_t)3 * 1216 * 512]) * bcl[m];
  }
#pragma unroll
  for (int n = 0; n < 8; n++) {
    float v = lm[n];
#pragma unroll
    for (int m = 0; m < 8; m++) v += gw1l[n * 8 + m] * lm[m];
    float t = fmaxf(v, 0.f) + gal[n] * fminf(v, 0.f);
    tbuf[((size_t)((b * N_ + n) * K_ + k)) * C_ + c] = f2bf(t);
  }
}

// ---------------- small GEMM body (M=1280 padded): C = A.Bw^T (+bias) --------
template <int KDIM, int NDIM, bool BIAS>
__device__ __forceinline__ void gemm_small_body(int bidx,
                                                const u16* __restrict__ A,
                                                const u16* __restrict__ Bw,
                                                const float* __restrict__ bias,
                                                float* __restrict__ f32out,
                                                u16* __restrict__ bf16out,
                                                u16* As, u16* Bs) {
  constexpr int NT = NDIM / 128;
  int m0 = (bidx / NT) * 128;
  int n0 = (bidx % NT) * 128;
  int tid = threadIdx.x;
  int wave = tid >> 6, lane = tid & 63;
  int wm = (wave >> 1) * 64, wn = (wave & 1) * 64;
  int quad = lane >> 4, l16 = lane & 15;
  const u16* Ab = A + (size_t)m0 * KDIM;
  const u16* Bb = Bw + (size_t)n0 * KDIM;
  f32x4 acc[4][4] = {};
  for (int k0 = 0; k0 < KDIM; k0 += 64) {
    __syncthreads();
    stage128(Ab, KDIM, k0, As, wave, lane);
    stage128(Bb, KDIM, k0, Bs, wave, lane);
    __syncthreads();
#pragma unroll
    for (int kk = 0; kk < 2; kk++) {
      int qb_ = kk * 64 + quad * 16;
      bf16x8 af[4], bfv[4];
#pragma unroll
      for (int t = 0; t < 4; t++) {
        af[t] = frag(As, wm + t * 16 + l16, qb_);
        bfv[t] = frag(Bs, wn + t * 16 + l16, qb_);
      }
#pragma unroll
      for (int tm = 0; tm < 4; tm++)
#pragma unroll
        for (int tn = 0; tn < 4; tn++)
          acc[tm][tn] = __builtin_amdgcn_mfma_f32_16x16x32_bf16(af[tm], bfv[tn], acc[tm][tn], 0, 0, 0);
    }
  }
  float bv[4];
#pragma unroll
  for (int tn = 0; tn < 4; tn++)
    bv[tn] = BIAS ? bias[n0 + wn + tn * 16 + l16] : 0.f;
#pragma unroll
  for (int tm = 0; tm < 4; tm++) {
    int mm = m0 + wm + tm * 16 + quad * 4;
#pragma unroll
    for (int tn = 0; tn < 4; tn++) {
      int nn = n0 + wn + tn * 16 + l16;
#pragma unroll
      for (int reg = 0; reg < 4; reg++) {
        float v = acc[tm][tn][reg] + bv[tn];
        if (f32out) f32out[(size_t)(mm + reg) * NDIM + nn] = v;
        if (bf16out) bf16out[(size_t)(mm + reg) * NDIM + nn] = f2bf(v);
      }
    }
  }
}

template <int KDIM, int NDIM, bool BIAS>
__global__ __launch_bounds__(256) void gemm_small_kernel(const u16* __restrict__ A,
                                                         const u16* __restrict__ Bw,
                                                         const float* __restrict__ bias,
                                                         float* __restrict__ f32out,
                                                         u16* __restrict__ bf16out) {
  __shared__ __align__(16) u16 As[128 * 64];
  __shared__ __align__(16) u16 Bs[128 * 64];
  gemm_small_body<KDIM, NDIM, BIAS>(blockIdx.x, A, Bw, bias, f32out, bf16out, As, Bs);
}

// ---------------- glob + val body ----------------
__device__ __forceinline__ void glob_val_body(int bid,
                                              const float* __restrict__ locl2,
                                              const float* __restrict__ fw,
                                              const float* __restrict__ fb,
                                              const float* __restrict__ ra,
                                              const float* __restrict__ vw,
                                              const float* __restrict__ vb,
                                              float* __restrict__ valo,
                                              float* gl) {
  int k = bid % 19;
  int b = bid / 19;
  int tid = threadIdx.x;
  float fwr[8];
#pragma unroll
  for (int m = 0; m < 8; m++) fwr[m] = fw[m];
  float fbv = fb[0], rav = ra[0];
  const float* lb = locl2 + ((size_t)(b * N_) * K_ + k) * C_;
  for (int c = tid; c < C_; c += 256) {
    float v = fbv;
#pragma unroll
    for (int m = 0; m < 8; m++) v += fwr[m] * lb[(size_t)m * K_ * C_ + c];
    gl[c] = fmaxf(v, 0.f) + rav * fminf(v, 0.f);
  }
  __syncthreads();
  int i = tid;
  const float* wr = vw + (size_t)i * C_;
  float s = vb[i];
  for (int c4 = 0; c4 < C_; c4 += 4) {
    float4 wv = *(const float4*)&wr[c4];
    float4 tv = *(const float4*)&gl[c4];
    s += wv.x * tv.x + wv.y * tv.y + wv.z * tv.z + wv.w * tv.w;
  }
  valo[(size_t)bid * CI_ + i] = s;
}

// merged: blocks 0..19 = key-projection small GEMM; blocks 20..171 = glob_val
__global__ __launch_bounds__(256) void small2_globval_kernel(const u16* __restrict__ A,
                                                             const u16* __restrict__ Bw,
                                                             const float* __restrict__ bias,
                                                             float* __restrict__ keyo,
                                                             const float* __restrict__ locl2,
                                                             const float* __restrict__ fw,
                                                             const float* __restrict__ fb,
                                                             const float* __restrict__ ra,
                                                             const float* __restrict__ vw,
                                                             const float* __restrict__ vb,
                                                             float* __restrict__ valo) {
  __shared__ __align__(16) u16 As[128 * 64];
  __shared__ __align__(16) u16 Bs[128 * 64];
  if (blockIdx.x < 20) {
    gemm_small_body<512, 256, true>(blockIdx.x, A, Bw, bias, keyo, nullptr, As, Bs);
  } else {
    glob_val_body(blockIdx.x - 20, locl2, fw, fb, ra, vw, vb, valo, (float*)As);
  }
}

// ---------------- big MFMA GEMM (per-batch 8192 rows) ----------------
// XCD-aware swizzle: the NT blocks sharing an A row-panel land on the SAME XCD.
template <int KDIM, int NDIM, bool TRANS_OUT, bool BIAS, bool OUTBF16, bool BNSTAT>
__global__ __launch_bounds__(256) void gemm_big_kernel(const u16* __restrict__ A,
                                                       const u16* __restrict__ Bw,
                                                       const float* __restrict__ bias,
                                                       void* __restrict__ Cout,
                                                       float* __restrict__ sums,
                                                       float* __restrict__ sumsq) {
  __shared__ __align__(16) u16 As[128 * 64];
  __shared__ __align__(16) u16 Bs[128 * 64];
  constexpr int NT = NDIM / 128;
  int b = blockIdx.y;
  int d = blockIdx.x;
  int xcd = d & 7;
  int j = d >> 3;
  int m0 = (xcd + 8 * (j / NT)) * 128;
  int n0 = (j % NT) * 128;
  int tid = threadIdx.x;
  int wave = tid >> 6, lane = tid & 63;
  int wm = (wave >> 1) * 64, wn = (wave & 1) * 64;
  int quad = lane >> 4, l16 = lane & 15;
  const u16* Ab = A + (size_t)b * 8192 * KDIM + (size_t)m0 * KDIM;
  const u16* Bb = Bw + (size_t)n0 * KDIM;
  f32x4 acc[4][4] = {};
  for (int k0 = 0; k0 < KDIM; k0 += 64) {
    __syncthreads();
    stage128(Ab, KDIM, k0, As, wave, lane);
    stage128(Bb, KDIM, k0, Bs, wave, lane);
    __syncthreads();
#pragma unroll
    for (int kk = 0; kk < 2; kk++) {
      int qb_ = kk * 64 + quad * 16;
      bf16x8 af[4], bfv[4];
#pragma unroll
      for (int t = 0; t < 4; t++) {
        af[t] = frag(As, wm + t * 16 + l16, qb_);
        bfv[t] = frag(Bs, wn + t * 16 + l16, qb_);
      }
#pragma unroll
      for (int tm = 0; tm < 4; tm++)
#pragma unroll
        for (int tn = 0; tn < 4; tn++)
          acc[tm][tn] = __builtin_amdgcn_mfma_f32_16x16x32_bf16(af[tm], bfv[tn], acc[tm][tn], 0, 0, 0);
    }
  }
  if constexpr (!TRANS_OUT) {
    float bv[4];
#pragma unroll
    for (int tn = 0; tn < 4; tn++)
      bv[tn] = BIAS ? bias[n0 + wn + tn * 16 + l16] : 0.f;
#pragma unroll
    for (int tm = 0; tm < 4; tm++) {
      int mm = m0 + wm + tm * 16 + quad * 4;
#pragma unroll
      for (int tn = 0; tn < 4; tn++) {
        int nn = n0 + wn + tn * 16 + l16;
        if constexpr (OUTBF16) {
          u16* C = (u16*)Cout + (size_t)b * 8192 * NDIM;
#pragma unroll
          for (int reg = 0; reg < 4; reg++)
            C[(size_t)(mm + reg) * NDIM + nn] = f2bf(acc[tm][tn][reg] + bv[tn]);
        } else {
          float* C = (float*)Cout + (size_t)b * 8192 * NDIM;
#pragma unroll
          for (int reg = 0; reg < 4; reg++)
            C[(size_t)(mm + reg) * NDIM + nn] = acc[tm][tn][reg] + bv[tn];
        }
      }
    }
  } else {
    float* C = (float*)Cout + (size_t)b * NDIM * 8192;
#pragma unroll
    for (int tm = 0; tm < 4; tm++) {
      int mm = m0 + wm + tm * 16 + quad * 4;
#pragma unroll
      for (int tn = 0; tn < 4; tn++) {
        int nn = n0 + wn + tn * 16 + l16;
        *(f32x4*)&C[(size_t)nn * 8192 + mm] = acc[tm][tn];
      }
    }
    if constexpr (BNSTAT) {
#pragma unroll
      for (int tn = 0; tn < 4; tn++) {
        int nn = n0 + wn + tn * 16 + l16;
        float s = 0.f, q = 0.f;
#pragma unroll
        for (int tm = 0; tm < 4; tm++)
#pragma unroll
          for (int reg = 0; reg < 4; reg++) {
            float v = acc[tm][tn][reg];
            s += v;
            q += v * v;
          }
        s += __shfl_xor(s, 16, 64); q += __shfl_xor(q, 16, 64);
        s += __shfl_xor(s, 32, 64); q += __shfl_xor(q, 32, 64);
        if (quad == 0) {
          atomicAdd(&sums[nn], s);
          atomicAdd(&sumsq[nn], q);
        }
      }
    }
  }
}

// ---------------- attention ----------------
__global__ __launch_bounds__(256) void attn2_kernel(const u16* __restrict__ q,
                                                    const float* __restrict__ keyo,
                                                    const float* __restrict__ valo,
                                                    u16* __restrict__ obuf) {
  __shared__ float keyl[19 * 256];
  __shared__ float vall[19 * 256];
  __shared__ float aff[128 * 20];
  int bid = blockIdx.x;
  int rg = bid & 7;
  int n = (bid >> 3) & 7;
  int b = bid >> 6;
  int bh = n >> 2, bw = n & 3;
  int tid = threadIdx.x;
  const float* ksrc = keyo + (size_t)((b * 8 + n) * 19) * 256;
  for (int e = tid; e < 19 * 256; e += 256) keyl[e] = ksrc[e];
  __syncthreads();
  if (tid < 128) {
    int r = rg * 4 + (tid >> 5);
    int wc = tid & 31;
    int hw = (bh * 32 + r) * W_ + bw * 32 + wc;
    const u16* qr = q + ((size_t)b * HW_ + hw) * 256;
    float acc[19];
#pragma unroll
    for (int k = 0; k < 19; k++) acc[k] = 0.f;
    for (int i0 = 0; i0 < 256; i0 += 8) {
      uint4 v = *(const uint4*)&qr[i0];
      float f0 = __uint_as_float((v.x & 0xFFFFu) << 16);
      float f1 = __uint_as_float(v.x & 0xFFFF0000u);
      float f2 = __uint_as_float((v.y & 0xFFFFu) << 16);
      float f3 = __uint_as_float(v.y & 0xFFFF0000u);
      float f4 = __uint_as_float((v.z & 0xFFFFu) << 16);
      float f5 = __uint_as_float(v.z & 0xFFFF0000u);
      float f6 = __uint_as_float((v.w & 0xFFFFu) << 16);
      float f7 = __uint_as_float(v.w & 0xFFFF0000u);
#pragma unroll
      for (int k = 0; k < 19; k++) {
        const float* kr = &keyl[k * 256 + i0];
        acc[k] += f0 * kr[0] + f1 * kr[1] + f2 * kr[2] + f3 * kr[3] +
                  f4 * kr[4] + f5 * kr[5] + f6 * kr[6] + f7 * kr[7];
      }
    }
    float mx = -1e30f;
#pragma unroll
    for (int k = 0; k < 19; k++) mx = fmaxf(mx, acc[k]);
    float se = 0.f;
#pragma unroll
    for (int k = 0; k < 19; k++) { acc[k] = __expf(acc[k] - mx); se += acc[k]; }
    float inv = 1.f / se;
#pragma unroll
    for (int k = 0; k < 19; k++) aff[tid * 20 + k] = acc[k] * inv;
  } else {
    const float* vsrc = valo + (size_t)b * 19 * 256;
    for (int e = tid - 128; e < 19 * 256; e += 128) vall[e] = vsrc[e];
  }
  __syncthreads();
  int px = tid & 127;
  int ih = (tid >> 7) * 128;
  int r3 = rg * 4 + (px >> 5);
  int wc3 = px & 31;
  int hw3 = (bh * 32 + r3) * W_ + bw * 32 + wc3;
  float av[19];
#pragma unroll
  for (int k = 0; k < 19; k++) av[k] = aff[px * 20 + k];
  u16* ob = obuf + ((size_t)b * HW_ + hw3) * 256 + ih;
  for (int i0 = 0; i0 < 128; i0 += 16) {
    float o16[16];
#pragma unroll
    for (int j = 0; j < 16; j++) o16[j] = 0.f;
#pragma unroll
    for (int k = 0; k < 19; k++) {
      float a = av[k];
      const float* vr = &vall[k * 256 + ih + i0];
#pragma unroll
      for (int j = 0; j < 16; j++) o16[j] += a * vr[j];
    }
    uint4 w0, w1;
    w0.x = (u32)f2bf(o16[0]) | ((u32)f2bf(o16[1]) << 16);
    w0.y = (u32)f2bf(o16[2]) | ((u32)f2bf(o16[3]) << 16);
    w0.z = (u32)f2bf(o16[4]) | ((u32)f2bf(o16[5]) << 16);
    w0.w = (u32)f2bf(o16[6]) | ((u32)f2bf(o16[7]) << 16);
    w1.x = (u32)f2bf(o16[8]) | ((u32)f2bf(o16[9]) << 16);
    w1.y = (u32)f2bf(o16[10]) | ((u32)f2bf(o16[11]) << 16);
    w1.z = (u32)f2bf(o16[12]) | ((u32)f2bf(o16[13]) << 16);
    w1.w = (u32)f2bf(o16[14]) | ((u32)f2bf(o16[15]) << 16);
    *(uint4*)&ob[i0] = w0;
    *(uint4*)&ob[i0 + 8] = w1;
  }
}

// ---------------- final: BN(scale/shift computed inline) + PReLU + residual ----------------
// block covers a 4096-float window inside one 8192-float c-row -> c uniform per block
__global__ __launch_bounds__(256) void final_kernel(const float* __restrict__ x,
                                                    const float* __restrict__ sums,
                                                    const float* __restrict__ sumsq,
                                                    const float* __restrict__ gamma,
                                                    const float* __restrict__ beta,
                                                    const float* __restrict__ oa,
                                                    float* __restrict__ out) {
  size_t base = (size_t)blockIdx.x * 4096 + threadIdx.x * 4;
  int c = (int)((base >> 13) & 511);
  const float inv_cnt = 1.f / 65536.f;
  float mu = sums[c] * inv_cnt;
  float var = sumsq[c] * inv_cnt - mu * mu;
  float iv = rsqrtf(var + 1e-5f);
  float sc = gamma[c] * iv;
  float sh = beta[c] - mu * sc;
  float a = oa[c];
#pragma unroll
  for (int jj = 0; jj < 4; jj++) {
    size_t idx = base + (size_t)jj * 1024;
    float4 y = *(float4*)&out[idx];
    float4 xv = *(const float4*)&x[idx];
    float4 r;
    float t;
    t = y.x * sc + sh; r.x = xv.x + fmaxf(t, 0.f) + a * fminf(t, 0.f);
    t = y.y * sc + sh; r.y = xv.y + fmaxf(t, 0.f) + a * fminf(t, 0.f);
    t = y.z * sc + sh; r.z = xv.z + fmaxf(t, 0.f) + a * fminf(t, 0.f);
    t = y.w * sc + sh; r.w = xv.w + fmaxf(t, 0.f) + a * fminf(t, 0.f);
    *(float4*)&out[idx] = r;
  }
}

extern "C" void kernel_launch(void* const* d_in, const int* in_sizes, int n_in,
                              void* d_out, int out_size, void* d_ws, size_t ws_size,
                              hipStream_t stream) {
  const float* x     = (const float*)d_in[0];
  const float* camw  = (const float*)d_in[1];
  const float* camb  = (const float*)d_in[2];
  const float* gw1   = (const float*)d_in[3];
  const float* ga    = (const float*)d_in[4];
  const float* gw2   = (const float*)d_in[5];
  const float* fw    = (const float*)d_in[6];
  const float* fb    = (const float*)d_in[7];
  const float* ra    = (const float*)d_in[8];
  const float* qw    = (const float*)d_in[9];
  const float* qb    = (const float*)d_in[10];
  const float* kw    = (const float*)d_in[11];
  const float* kb    = (const float*)d_in[12];
  const float* vw    = (const float*)d_in[13];
  const float* vb    = (const float*)d_in[14];
  const float* ow    = (const float*)d_in[15];
  const float* gamma = (const float*)d_in[16];
  const float* beta  = (const float*)d_in[17];
  const float* oa    = (const float*)d_in[18];
  float* out = (float*)d_out;
  float* ws = (float*)d_ws;

  // ---- workspace layout (float units) ----
  float* cam    = ws;                    // 1,245,184
  float* bconf  = cam + 1245184;         // 2,048 pad
  float* pconf  = bconf + 2048;          // 1,245,184
  float* locl   = pconf + 1245184;       // 622,592 (unused, layout kept)
  float* locl2f = locl + 622592;         // 1280*512 = 655,360
  float* keyo   = locl2f + 655360;       // 1280*256 = 327,680
  float* valo   = keyo + 327680;         // 38,912
  float* sums   = valo + 38912;          // 512
  float* sumsq  = sums + 512;            // 512
  float* scale  = sumsq + 512;           // 512 (unused)
  float* shift  = scale + 512;           // 512 (unused)
  u16* qwbf   = (u16*)(shift + 512);     // 131,072
  u16* owbf   = qwbf + 131072;           // 131,072
  u16* kwbf   = owbf + 131072;           // 131,072
  u16* gw2bf  = kwbf + 131072;           // 262,144
  u16* camwbf = gw2bf + 262144;          // 16,384 (32x512)
  u16* tbuf   = camwbf + 16384;          // 1280*512 = 655,360
  u16* l2bf   = tbuf + 655360;           // 1280*512 = 655,360
  u16* xt     = l2bf + 655360;           // 33,554,432 (64 MB)
  u16* obuf   = xt;                      // overlay: all xt readers precede attn2
  u16* qbuf   = xt + 33554432;           // 16,777,216 (32 MB)
  float* part = (float*)qbuf;            // overlay: consumed before qproj

  xpose_prep_kernel<<<8865, 256, 0, stream>>>(x, xt, qw, ow, kw, gw2, camw,
                                              qwbf, owbf, kwbf, gw2bf, camwbf,
                                              sums, (float*)(tbuf + 1216 * 512));
  gemm_cam_kernel<<<dim3(64, 8), 256, 0, stream>>>(xt, camwbf, camb, cam);
  softcls_kernel<<<1216, 256, 0, stream>>>(cam, bconf, pconf);
  local_part_kernel<<<512, 256, 0, stream>>>(xt, pconf, part);
  t_kernel<<<304, 256, 0, stream>>>(part, bconf, gw1, ga, tbuf);
  gemm_small_kernel<512, 512, false>
      <<<40, 256, 0, stream>>>(tbuf, gw2bf, nullptr, locl2f, l2bf);
  small2_globval_kernel<<<172, 256, 0, stream>>>(l2bf, kwbf, kb, keyo,
                                                 locl2f, fw, fb, ra, vw, vb, valo);
  gemm_big_kernel<512, 256, false, true, true, false>
      <<<dim3(128, 8), 256, 0, stream>>>(xt, qwbf, qb, qbuf, nullptr, nullptr);
  attn2_kernel<<<512, 256, 0, stream>>>(qbuf, keyo, valo, obuf);
  gemm_big_kernel<256, 512, true, false, false, true>
      <<<dim3(256, 8), 256, 0, stream>>>(obuf, owbf, nullptr, out, sums, sumsq);
  final_kernel<<<8192, 256, 0, stream>>>(x, sums, sumsq, gamma, beta, oa, out);
}

// Round 3
// 527.829 us; speedup vs baseline: 1.0954x; 1.0407x over previous
//
#include <hip/hip_runtime.h>
#include <cstdint>
#include <cstddef>

#define B_ 8
#define C_ 512
#define H_ 64
#define W_ 128
#define HW_ 8192
#define K_ 19
#define N_ 8
#define P_ 1024
#define CI_ 256

typedef unsigned short u16;
typedef unsigned int u32;
typedef __attribute__((ext_vector_type(8))) short bf16x8;   // 8 bf16 (4 VGPRs)
typedef __attribute__((ext_vector_type(4))) float f32x4;    // 4 fp32 acc

__device__ __forceinline__ u16 f2bf(float f) {
  u32 u = __float_as_uint(f);
  u32 r = (u + 0x7FFFu + ((u >> 16) & 1u)) >> 16;
  return (u16)r;
}
__device__ __forceinline__ float bf2f(u16 h) {
  return __uint_as_float(((u32)h) << 16);
}

// async global->LDS, 16B per lane; LDS dest is wave-uniform base + lane*16
__device__ __forceinline__ void gload16(const u16* g, u16* l) {
  __builtin_amdgcn_global_load_lds(
      (const __attribute__((address_space(1))) unsigned int*)g,
      (__attribute__((address_space(3))) unsigned int*)l, 16, 0, 0);
}

// ---- swizzled tile staging: tile rows of 64 u16 (128B), chunk-XOR swizzle ----
__device__ __forceinline__ void stage128(const u16* __restrict__ src, size_t ld, int k0,
                                         u16* lds, int wave, int lane) {
  int rsub = lane >> 3;                       // 0..7 row within wave-instr
  int swz = ((lane & 7) ^ rsub) << 3;         // u16 offset within row (16B chunks)
#pragma unroll
  for (int i = 0; i < 4; i++) {
    int rowbase = wave * 8 + i * 32;
    gload16(src + (size_t)(rowbase + rsub) * ld + k0 + swz, lds + rowbase * 64);
  }
}
__device__ __forceinline__ void stage32(const u16* __restrict__ src, size_t ld, int k0,
                                        u16* lds, int wave, int lane) {
  int rsub = lane >> 3;
  int swz = ((lane & 7) ^ rsub) << 3;
  int rowbase = wave * 8;
  gload16(src + (size_t)(rowbase + rsub) * ld + k0 + swz, lds + rowbase * 64);
}
__device__ __forceinline__ bf16x8 frag(const u16* lds, int row, int qbyte) {
  return *(const bf16x8*)((const char*)lds + row * 128 + (qbyte ^ ((row & 7) << 4)));
}

// ---------------- block reductions (256 threads = 4 waves) ----------------
__device__ __forceinline__ float blockSum256(float v, float* red4) {
#pragma unroll
  for (int o = 32; o > 0; o >>= 1) v += __shfl_down(v, o, 64);
  __syncthreads();
  if ((threadIdx.x & 63) == 0) red4[threadIdx.x >> 6] = v;
  __syncthreads();
  return red4[0] + red4[1] + red4[2] + red4[3];
}

__device__ __forceinline__ float blockMax256(float v, float* red4) {
#pragma unroll
  for (int o = 32; o > 0; o >>= 1) v = fmaxf(v, __shfl_down(v, o, 64));
  __syncthreads();
  if ((threadIdx.x & 63) == 0) red4[threadIdx.x >> 6] = v;
  __syncthreads();
  return fmaxf(fmaxf(red4[0], red4[1]), fmaxf(red4[2], red4[3]));
}

__device__ __forceinline__ void cvt4(const float* __restrict__ s, u16* __restrict__ d, int i) {
  float4 v = *(const float4*)&s[(size_t)i * 4];
  ushort4 o;
  o.x = f2bf(v.x); o.y = f2bf(v.y); o.z = f2bf(v.z); o.w = f2bf(v.w);
  *(ushort4*)&d[(size_t)i * 4] = o;
}

// ---------------- fused transpose + prologue ----------------
__global__ __launch_bounds__(256) void xpose_prep_kernel(const float* __restrict__ x,
                                                         u16* __restrict__ xt,
                                                         const float* __restrict__ qw,
                                                         const float* __restrict__ ow,
                                                         const float* __restrict__ kw,
                                                         const float* __restrict__ gw2,
                                                         const float* __restrict__ camw,
                                                         u16* __restrict__ qwbf,
                                                         u16* __restrict__ owbf,
                                                         u16* __restrict__ kwbf,
                                                         u16* __restrict__ gw2bf,
                                                         u16* __restrict__ camwbf,
                                                         float* __restrict__ sums,
                                                         float* __restrict__ tpad) {
  __shared__ float tile[64][65];
  int bid = blockIdx.x;
  int tid = threadIdx.x;
  if (bid >= 8192) {
    int pb = bid - 8192;
    if (pb < 128) {
      cvt4(qw, qwbf, pb * 256 + tid);
    } else if (pb < 256) {
      cvt4(ow, owbf, (pb - 128) * 256 + tid);
    } else if (pb < 384) {
      cvt4(kw, kwbf, (pb - 256) * 256 + tid);
    } else if (pb < 640) {
      cvt4(gw2, gw2bf, (pb - 384) * 256 + tid);
    } else if (pb < 656) {
      int i = (pb - 640) * 256 + tid;
      if (i * 4 < K_ * C_) {
        cvt4(camw, camwbf, i);
      } else {
        ushort4 z; z.x = 0; z.y = 0; z.z = 0; z.w = 0;
        *(ushort4*)&camwbf[(size_t)i * 4] = z;
      }
    } else if (pb == 656) {
      float4 z; z.x = 0.f; z.y = 0.f; z.z = 0.f; z.w = 0.f;
      *(float4*)&sums[tid * 4] = z;  // sums(512)+sumsq(512) contiguous
    } else {
      int i = (pb - 657) * 256 + tid;
      float4 z; z.x = 0.f; z.y = 0.f; z.z = 0.f; z.w = 0.f;
      *(float4*)&tpad[(size_t)i * 4] = z;
    }
    return;
  }
  int hw0 = (bid & 127) << 6;
  int c0 = ((bid >> 7) & 7) << 6;
  int b = bid >> 10;
  int r = tid >> 4;
  int col4 = (tid & 15) << 2;
  const float* xb = x + ((size_t)b * C_ + c0) * HW_ + hw0;
#pragma unroll
  for (int it = 0; it < 4; it++) {
    int rr = r + it * 16;
    float4 v = *(const float4*)&xb[(size_t)rr * HW_ + col4];
    tile[rr][col4 + 0] = v.x;
    tile[rr][col4 + 1] = v.y;
    tile[rr][col4 + 2] = v.z;
    tile[rr][col4 + 3] = v.w;
  }
  __syncthreads();
  u16* xo = xt + ((size_t)b * HW_ + hw0) * C_ + c0;
#pragma unroll
  for (int it = 0; it < 4; it++) {
    int hwr = r + it * 16;
    ushort4 o;
    o.x = f2bf(tile[col4 + 0][hwr]);
    o.y = f2bf(tile[col4 + 1][hwr]);
    o.z = f2bf(tile[col4 + 2][hwr]);
    o.w = f2bf(tile[col4 + 3][hwr]);
    *(ushort4*)&xo[(size_t)hwr * C_ + col4] = o;
  }
}

// ---------------- cam via MFMA ----------------
__global__ __launch_bounds__(256) void gemm_cam_kernel(const u16* __restrict__ A,
                                                       const u16* __restrict__ Bw,
                                                       const float* __restrict__ bias,
                                                       float* __restrict__ cam) {
  __shared__ __align__(16) u16 As[128 * 64];
  __shared__ __align__(16) u16 Bs[32 * 64];
  int b = blockIdx.y;
  int m0 = blockIdx.x * 128;
  int tid = threadIdx.x;
  int wave = tid >> 6, lane = tid & 63;
  int wm = wave * 32;
  int quad = lane >> 4, l16 = lane & 15;
  const u16* Ab = A + (size_t)b * HW_ * C_ + (size_t)m0 * C_;
  f32x4 acc[2][2] = {};
  for (int k0 = 0; k0 < C_; k0 += 64) {
    __syncthreads();
    stage128(Ab, C_, k0, As, wave, lane);
    stage32(Bw, C_, k0, Bs, wave, lane);
    __syncthreads();
#pragma unroll
    for (int kk = 0; kk < 2; kk++) {
      int qb_ = kk * 64 + quad * 16;
      bf16x8 af[2], bfv[2];
#pragma unroll
      for (int t = 0; t < 2; t++) {
        af[t] = frag(As, wm + t * 16 + l16, qb_);
        bfv[t] = frag(Bs, t * 16 + l16, qb_);
      }
#pragma unroll
      for (int tm = 0; tm < 2; tm++)
#pragma unroll
        for (int tn = 0; tn < 2; tn++)
          acc[tm][tn] = __builtin_amdgcn_mfma_f32_16x16x32_bf16(af[tm], bfv[tn], acc[tm][tn], 0, 0, 0);
    }
  }
  float* C = cam + (size_t)b * K_ * HW_;
#pragma unroll
  for (int tm = 0; tm < 2; tm++) {
    int mm = m0 + wm + tm * 16 + quad * 4;
#pragma unroll
    for (int tn = 0; tn < 2; tn++) {
      int nn = tn * 16 + l16;
      if (nn < K_) {
        float bv = bias[nn];
        f32x4 v = acc[tm][tn];
        v[0] += bv; v[1] += bv; v[2] += bv; v[3] += bv;
        *(f32x4*)&C[(size_t)nn * HW_ + mm] = v;
      }
    }
  }
}

// ---------------- fused cls+softmax ----------------
__global__ __launch_bounds__(256) void softcls_kernel(const float* __restrict__ cam,
                                                      float* __restrict__ bconf,
                                                      float* __restrict__ pconf) {
  __shared__ float red4[4];
  int bid = blockIdx.x;
  int k = bid % 19;
  int n = (bid / 19) & 7;
  int b = bid / 152;
  int bh = n >> 2, bw = n & 3;
  const float* base = cam + ((size_t)b * K_ + k) * HW_ + (bh * 32) * W_ + bw * 32;
  float v[4];
  float s = 0.f, mx = -1e30f;
#pragma unroll
  for (int j = 0; j < 4; j++) {
    int p = threadIdx.x + j * 256;
    v[j] = base[(p >> 5) * W_ + (p & 31)];
    s += v[j];
    mx = fmaxf(mx, v[j]);
  }
  float tot = blockSum256(s, red4);
  if (threadIdx.x == 0) {
    float m = tot * (1.f / 1024.f);
    bconf[bid] = 1.f / (1.f + __expf(-m));
  }
  mx = blockMax256(mx, red4);
  float e[4];
  float se = 0.f;
#pragma unroll
  for (int j = 0; j < 4; j++) { e[j] = __expf(v[j] - mx); se += e[j]; }
  se = blockSum256(se, red4);
  float inv = 1.f / se;
  float* outp = pconf + (size_t)bid * P_;
#pragma unroll
  for (int j = 0; j < 4; j++) outp[threadIdx.x + j * 256] = e[j] * inv;
}

// ---------------- big GEMM body (per-batch 8192 rows), shared-LDS version ----
// XCD swizzle: NT blocks sharing an A panel land on the same XCD.
template <int KDIM, int NDIM, bool TRANS_OUT, bool BIAS, bool OUTBF16, bool BNSTAT>
__device__ __forceinline__ void gemm_big_body(int bx, int b,
                                              const u16* __restrict__ A,
                                              const u16* __restrict__ Bw,
                                              const float* __restrict__ bias,
                                              void* __restrict__ Cout,
                                              float* __restrict__ sums,
                                              float* __restrict__ sumsq,
                                              u16* As, u16* Bs) {
  constexpr int NT = NDIM / 128;
  int xcd = bx & 7;
  int j = bx >> 3;
  int m0 = (xcd + 8 * (j / NT)) * 128;
  int n0 = (j % NT) * 128;
  int tid = threadIdx.x;
  int wave = tid >> 6, lane = tid & 63;
  int wm = (wave >> 1) * 64, wn = (wave & 1) * 64;
  int quad = lane >> 4, l16 = lane & 15;
  const u16* Ab = A + (size_t)b * 8192 * KDIM + (size_t)m0 * KDIM;
  const u16* Bb = Bw + (size_t)n0 * KDIM;
  f32x4 acc[4][4] = {};
  for (int k0 = 0; k0 < KDIM; k0 += 64) {
    __syncthreads();
    stage128(Ab, KDIM, k0, As, wave, lane);
    stage128(Bb, KDIM, k0, Bs, wave, lane);
    __syncthreads();
#pragma unroll
    for (int kk = 0; kk < 2; kk++) {
      int qb_ = kk * 64 + quad * 16;
      bf16x8 af[4], bfv[4];
#pragma unroll
      for (int t = 0; t < 4; t++) {
        af[t] = frag(As, wm + t * 16 + l16, qb_);
        bfv[t] = frag(Bs, wn + t * 16 + l16, qb_);
      }
#pragma unroll
      for (int tm = 0; tm < 4; tm++)
#pragma unroll
        for (int tn = 0; tn < 4; tn++)
          acc[tm][tn] = __builtin_amdgcn_mfma_f32_16x16x32_bf16(af[tm], bfv[tn], acc[tm][tn], 0, 0, 0);
    }
  }
  if constexpr (!TRANS_OUT) {
    float bv[4];
#pragma unroll
    for (int tn = 0; tn < 4; tn++)
      bv[tn] = BIAS ? bias[n0 + wn + tn * 16 + l16] : 0.f;
#pragma unroll
    for (int tm = 0; tm < 4; tm++) {
      int mm = m0 + wm + tm * 16 + quad * 4;
#pragma unroll
      for (int tn = 0; tn < 4; tn++) {
        int nn = n0 + wn + tn * 16 + l16;
        if constexpr (OUTBF16) {
          u16* C = (u16*)Cout + (size_t)b * 8192 * NDIM;
#pragma unroll
          for (int reg = 0; reg < 4; reg++)
            C[(size_t)(mm + reg) * NDIM + nn] = f2bf(acc[tm][tn][reg] + bv[tn]);
        } else {
          float* C = (float*)Cout + (size_t)b * 8192 * NDIM;
#pragma unroll
          for (int reg = 0; reg < 4; reg++)
            C[(size_t)(mm + reg) * NDIM + nn] = acc[tm][tn][reg] + bv[tn];
        }
      }
    }
  } else {
#pragma unroll
    for (int tm = 0; tm < 4; tm++) {
      int mm = m0 + wm + tm * 16 + quad * 4;
#pragma unroll
      for (int tn = 0; tn < 4; tn++) {
        int nn = n0 + wn + tn * 16 + l16;
        if constexpr (OUTBF16) {
          u16* C = (u16*)Cout + (size_t)b * NDIM * 8192;
          ushort4 o;
          o.x = f2bf(acc[tm][tn][0]);
          o.y = f2bf(acc[tm][tn][1]);
          o.z = f2bf(acc[tm][tn][2]);
          o.w = f2bf(acc[tm][tn][3]);
          *(ushort4*)&C[(size_t)nn * 8192 + mm] = o;
        } else {
          float* C = (float*)Cout + (size_t)b * NDIM * 8192;
          *(f32x4*)&C[(size_t)nn * 8192 + mm] = acc[tm][tn];
        }
      }
    }
    if constexpr (BNSTAT) {
#pragma unroll
      for (int tn = 0; tn < 4; tn++) {
        int nn = n0 + wn + tn * 16 + l16;
        float s = 0.f, q = 0.f;
#pragma unroll
        for (int tm = 0; tm < 4; tm++)
#pragma unroll
          for (int reg = 0; reg < 4; reg++) {
            float v = acc[tm][tn][reg];
            s += v;
            q += v * v;
          }
        s += __shfl_xor(s, 16, 64); q += __shfl_xor(q, 16, 64);
        s += __shfl_xor(s, 32, 64); q += __shfl_xor(q, 32, 64);
        if (quad == 0) {
          atomicAdd(&sums[nn], s);
          atomicAdd(&sumsq[nn], q);
        }
      }
    }
  }
}

template <int KDIM, int NDIM, bool TRANS_OUT, bool BIAS, bool OUTBF16, bool BNSTAT>
__global__ __launch_bounds__(256) void gemm_big_kernel(const u16* __restrict__ A,
                                                       const u16* __restrict__ Bw,
                                                       const float* __restrict__ bias,
                                                       void* __restrict__ Cout,
                                                       float* __restrict__ sums,
                                                       float* __restrict__ sumsq) {
  __shared__ __align__(16) u16 As[128 * 64];
  __shared__ __align__(16) u16 Bs[128 * 64];
  gemm_big_body<KDIM, NDIM, TRANS_OUT, BIAS, OUTBF16, BNSTAT>(
      blockIdx.x, blockIdx.y, A, Bw, bias, Cout, sums, sumsq, As, Bs);
}

// ---------------- local partial body ----------------
__device__ __forceinline__ void local_part_body(int bid,
                                                const u16* __restrict__ xt,
                                                const float* __restrict__ pconf,
                                                float* __restrict__ part,
                                                float* pcl) {
  int pq = bid & 3;
  int half = (bid >> 2) & 1;
  int n = (bid >> 3) & 7;
  int b = bid >> 6;
  int tid = threadIdx.x;
  int c = half * 256 + tid;
  int bh = n >> 2, bw = n & 3;
  const float* pcb = pconf + (size_t)((b * N_ + n) * K_) * P_ + pq * 256;
  for (int e = tid; e < 19 * 64; e += 256) {
    int k = e >> 6, q4 = e & 63;
    *(float4*)&pcl[k * 256 + q4 * 4] = *(const float4*)&pcb[(size_t)k * P_ + q4 * 4];
  }
  __syncthreads();
  float acc[K_];
#pragma unroll
  for (int k = 0; k < K_; k++) acc[k] = 0.f;
  const u16* xb = xt + (size_t)b * HW_ * C_ + c;
  for (int pl0 = 0; pl0 < 256; pl0 += 8) {
    float xv[8];
#pragma unroll
    for (int g = 0; g < 2; g++) {
      int p = pq * 256 + pl0 + g * 4;
      int hw = (bh * 32 + (p >> 5)) * W_ + bw * 32 + (p & 31);
      const u16* xr = xb + (size_t)hw * C_;
#pragma unroll
      for (int j = 0; j < 4; j++) xv[g * 4 + j] = bf2f(xr[(size_t)j * C_]);
    }
#pragma unroll
    for (int k = 0; k < K_; k++) {
      float4 p0 = *(const float4*)&pcl[k * 256 + pl0];
      float4 p1 = *(const float4*)&pcl[k * 256 + pl0 + 4];
      acc[k] += p0.x * xv[0] + p0.y * xv[1] + p0.z * xv[2] + p0.w * xv[3]
              + p1.x * xv[4] + p1.y * xv[5] + p1.z * xv[6] + p1.w * xv[7];
    }
  }
  int row = (b * N_ + n) * K_;
  float* pp = part + ((size_t)pq * 1216 + row) * C_ + c;
#pragma unroll
  for (int k = 0; k < K_; k++) pp[(size_t)k * C_] = acc[k];
}

// merged: local_part (512) + qproj chunk b=0,1 (256)
__global__ __launch_bounds__(256) void local_part_q_kernel(const u16* __restrict__ xt,
                                                           const float* __restrict__ pconf,
                                                           float* __restrict__ part,
                                                           const u16* __restrict__ qwbf,
                                                           const float* __restrict__ qb,
                                                           u16* __restrict__ qbuf) {
  __shared__ __align__(16) u16 smem[16384];  // 32 KB
  int bid = blockIdx.x;
  if (bid < 512) {
    local_part_body(bid, xt, pconf, part, (float*)smem);
  } else {
    int cb = bid - 512;
    gemm_big_body<512, 256, false, true, true, false>(cb & 127, cb >> 7, xt, qwbf, qb,
                                                      qbuf, nullptr, nullptr,
                                                      smem, smem + 8192);
  }
}

// merged: t (304) + qproj chunk b=2,3 (256)
__global__ __launch_bounds__(256) void t_q_kernel(const float* __restrict__ part,
                                                  const float* __restrict__ bconf,
                                                  const float* __restrict__ gw1,
                                                  const float* __restrict__ ga,
                                                  u16* __restrict__ tbuf,
                                                  const u16* __restrict__ xt,
                                                  const u16* __restrict__ qwbf,
                                                  const float* __restrict__ qb,
                                                  u16* __restrict__ qbuf) {
  __shared__ __align__(16) u16 smem[16384];
  int bid = blockIdx.x;
  int tid = threadIdx.x;
  if (bid >= 304) {
    int cb = bid - 304;
    gemm_big_body<512, 256, false, true, true, false>(cb & 127, 2 + (cb >> 7), xt, qwbf, qb,
                                                      qbuf, nullptr, nullptr,
                                                      smem, smem + 8192);
    return;
  }
  float* gw1l = (float*)smem;        // 64
  float* gal = gw1l + 64;            // 8
  float* bcl = gal + 8;              // 8
  int half = bid & 1;
  int rem = bid >> 1;
  int k = rem % 19;
  int b = rem / 19;
  if (tid < 64) gw1l[tid] = gw1[tid];
  if (tid < 8) {
    gal[tid] = ga[tid];
    bcl[tid] = bconf[(size_t)(b * 8 + tid) * 19 + k];
  }
  __syncthreads();
  int c = half * 256 + tid;
  float lm[8];
#pragma unroll
  for (int m = 0; m < 8; m++) {
    size_t off = ((size_t)(b * N_ + m) * K_ + k) * C_ + c;
    lm[m] = (part[off] + part[off + (size_t)1216 * 512] +
             part[off + (size_t)2 * 1216 * 512] + part[off + (size_t)3 * 1216 * 512]) * bcl[m];
  }
#pragma unroll
  for (int n = 0; n < 8; n++) {
    float v = lm[n];
#pragma unroll
    for (int m = 0; m < 8; m++) v += gw1l[n * 8 + m] * lm[m];
    float t = fmaxf(v, 0.f) + gal[n] * fminf(v, 0.f);
    tbuf[((size_t)((b * N_ + n) * K_ + k)) * C_ + c] = f2bf(t);
  }
}

// ---------------- small GEMM body (M=1280 padded) ----------------
template <int KDIM, int NDIM, bool BIAS>
__device__ __forceinline__ void gemm_small_body(int bidx,
                                                const u16* __restrict__ A,
                                                const u16* __restrict__ Bw,
                                                const float* __restrict__ bias,
                                                float* __restrict__ f32out,
                                                u16* __restrict__ bf16out,
                                                u16* As, u16* Bs) {
  constexpr int NT = NDIM / 128;
  int m0 = (bidx / NT) * 128;
  int n0 = (bidx % NT) * 128;
  int tid = threadIdx.x;
  int wave = tid >> 6, lane = tid & 63;
  int wm = (wave >> 1) * 64, wn = (wave & 1) * 64;
  int quad = lane >> 4, l16 = lane & 15;
  const u16* Ab = A + (size_t)m0 * KDIM;
  const u16* Bb = Bw + (size_t)n0 * KDIM;
  f32x4 acc[4][4] = {};
  for (int k0 = 0; k0 < KDIM; k0 += 64) {
    __syncthreads();
    stage128(Ab, KDIM, k0, As, wave, lane);
    stage128(Bb, KDIM, k0, Bs, wave, lane);
    __syncthreads();
#pragma unroll
    for (int kk = 0; kk < 2; kk++) {
      int qb_ = kk * 64 + quad * 16;
      bf16x8 af[4], bfv[4];
#pragma unroll
      for (int t = 0; t < 4; t++) {
        af[t] = frag(As, wm + t * 16 + l16, qb_);
        bfv[t] = frag(Bs, wn + t * 16 + l16, qb_);
      }
#pragma unroll
      for (int tm = 0; tm < 4; tm++)
#pragma unroll
        for (int tn = 0; tn < 4; tn++)
          acc[tm][tn] = __builtin_amdgcn_mfma_f32_16x16x32_bf16(af[tm], bfv[tn], acc[tm][tn], 0, 0, 0);
    }
  }
  float bv[4];
#pragma unroll
  for (int tn = 0; tn < 4; tn++)
    bv[tn] = BIAS ? bias[n0 + wn + tn * 16 + l16] : 0.f;
#pragma unroll
  for (int tm = 0; tm < 4; tm++) {
    int mm = m0 + wm + tm * 16 + quad * 4;
#pragma unroll
    for (int tn = 0; tn < 4; tn++) {
      int nn = n0 + wn + tn * 16 + l16;
#pragma unroll
      for (int reg = 0; reg < 4; reg++) {
        float v = acc[tm][tn][reg] + bv[tn];
        if (f32out) f32out[(size_t)(mm + reg) * NDIM + nn] = v;
        if (bf16out) bf16out[(size_t)(mm + reg) * NDIM + nn] = f2bf(v);
      }
    }
  }
}

// merged: small1 gemm (40) + qproj chunk b=4,5 (256)
__global__ __launch_bounds__(256) void small1_q_kernel(const u16* __restrict__ A,
                                                       const u16* __restrict__ Bw,
                                                       float* __restrict__ locl2f,
                                                       u16* __restrict__ l2bf,
                                                       const u16* __restrict__ xt,
                                                       const u16* __restrict__ qwbf,
                                                       const float* __restrict__ qb,
                                                       u16* __restrict__ qbuf) {
  __shared__ __align__(16) u16 smem[16384];
  int bid = blockIdx.x;
  if (bid < 40) {
    gemm_small_body<512, 512, false>(bid, A, Bw, nullptr, locl2f, l2bf, smem, smem + 8192);
  } else {
    int cb = bid - 40;
    gemm_big_body<512, 256, false, true, true, false>(cb & 127, 4 + (cb >> 7), xt, qwbf, qb,
                                                      qbuf, nullptr, nullptr,
                                                      smem, smem + 8192);
  }
}

// ---------------- glob + val body ----------------
__device__ __forceinline__ void glob_val_body(int bid,
                                              const float* __restrict__ locl2,
                                              const float* __restrict__ fw,
                                              const float* __restrict__ fb,
                                              const float* __restrict__ ra,
                                              const float* __restrict__ vw,
                                              const float* __restrict__ vb,
                                              float* __restrict__ valo,
                                              float* gl) {
  int k = bid % 19;
  int b = bid / 19;
  int tid = threadIdx.x;
  float fwr[8];
#pragma unroll
  for (int m = 0; m < 8; m++) fwr[m] = fw[m];
  float fbv = fb[0], rav = ra[0];
  const float* lb = locl2 + ((size_t)(b * N_) * K_ + k) * C_;
  for (int c = tid; c < C_; c += 256) {
    float v = fbv;
#pragma unroll
    for (int m = 0; m < 8; m++) v += fwr[m] * lb[(size_t)m * K_ * C_ + c];
    gl[c] = fmaxf(v, 0.f) + rav * fminf(v, 0.f);
  }
  __syncthreads();
  int i = tid;
  const float* wr = vw + (size_t)i * C_;
  float s = vb[i];
  for (int c4 = 0; c4 < C_; c4 += 4) {
    float4 wv = *(const float4*)&wr[c4];
    float4 tv = *(const float4*)&gl[c4];
    s += wv.x * tv.x + wv.y * tv.y + wv.z * tv.z + wv.w * tv.w;
  }
  valo[(size_t)bid * CI_ + i] = s;
}

// merged: small2 key gemm (20) + glob_val (152) + pad (4) + qproj chunk b=6,7 (256)
__global__ __launch_bounds__(256) void small2gv_q_kernel(const u16* __restrict__ A,
                                                         const u16* __restrict__ Bw,
                                                         const float* __restrict__ bias,
                                                         float* __restrict__ keyo,
                                                         const float* __restrict__ locl2,
                                                         const float* __restrict__ fw,
                                                         const float* __restrict__ fb,
                                                         const float* __restrict__ ra,
                                                         const float* __restrict__ vw,
                                                         const float* __restrict__ vb,
                                                         float* __restrict__ valo,
                                                         const u16* __restrict__ xt,
                                                         const u16* __restrict__ qwbf,
                                                         const float* __restrict__ qb,
                                                         u16* __restrict__ qbuf) {
  __shared__ __align__(16) u16 smem[16384];
  int bid = blockIdx.x;
  if (bid < 20) {
    gemm_small_body<512, 256, true>(bid, A, Bw, bias, keyo, nullptr, smem, smem + 8192);
  } else if (bid < 172) {
    glob_val_body(bid - 20, locl2, fw, fb, ra, vw, vb, valo, (float*)smem);
  } else if (bid >= 176) {
    int cb = bid - 176;
    gemm_big_body<512, 256, false, true, true, false>(cb & 127, 6 + (cb >> 7), xt, qwbf, qb,
                                                      qbuf, nullptr, nullptr,
                                                      smem, smem + 8192);
  }
}

// ---------------- attention ----------------
__global__ __launch_bounds__(256) void attn2_kernel(const u16* __restrict__ q,
                                                    const float* __restrict__ keyo,
                                                    const float* __restrict__ valo,
                                                    u16* __restrict__ obuf) {
  __shared__ float keyl[19 * 256];
  __shared__ float vall[19 * 256];
  __shared__ float aff[128 * 20];
  int bid = blockIdx.x;
  int rg = bid & 7;
  int n = (bid >> 3) & 7;
  int b = bid >> 6;
  int bh = n >> 2, bw = n & 3;
  int tid = threadIdx.x;
  const float* ksrc = keyo + (size_t)((b * 8 + n) * 19) * 256;
  for (int e = tid; e < 19 * 256; e += 256) keyl[e] = ksrc[e];
  __syncthreads();
  if (tid < 128) {
    int r = rg * 4 + (tid >> 5);
    int wc = tid & 31;
    int hw = (bh * 32 + r) * W_ + bw * 32 + wc;
    const u16* qr = q + ((size_t)b * HW_ + hw) * 256;
    float acc[19];
#pragma unroll
    for (int k = 0; k < 19; k++) acc[k] = 0.f;
    for (int i0 = 0; i0 < 256; i0 += 8) {
      uint4 v = *(const uint4*)&qr[i0];
      float f0 = __uint_as_float((v.x & 0xFFFFu) << 16);
      float f1 = __uint_as_float(v.x & 0xFFFF0000u);
      float f2 = __uint_as_float((v.y & 0xFFFFu) << 16);
      float f3 = __uint_as_float(v.y & 0xFFFF0000u);
      float f4 = __uint_as_float((v.z & 0xFFFFu) << 16);
      float f5 = __uint_as_float(v.z & 0xFFFF0000u);
      float f6 = __uint_as_float((v.w & 0xFFFFu) << 16);
      float f7 = __uint_as_float(v.w & 0xFFFF0000u);
#pragma unroll
      for (int k = 0; k < 19; k++) {
        const float* kr = &keyl[k * 256 + i0];
        acc[k] += f0 * kr[0] + f1 * kr[1] + f2 * kr[2] + f3 * kr[3] +
                  f4 * kr[4] + f5 * kr[5] + f6 * kr[6] + f7 * kr[7];
      }
    }
    float mx = -1e30f;
#pragma unroll
    for (int k = 0; k < 19; k++) mx = fmaxf(mx, acc[k]);
    float se = 0.f;
#pragma unroll
    for (int k = 0; k < 19; k++) { acc[k] = __expf(acc[k] - mx); se += acc[k]; }
    float inv = 1.f / se;
#pragma unroll
    for (int k = 0; k < 19; k++) aff[tid * 20 + k] = acc[k] * inv;
  } else {
    const float* vsrc = valo + (size_t)b * 19 * 256;
    for (int e = tid - 128; e < 19 * 256; e += 128) vall[e] = vsrc[e];
  }
  __syncthreads();
  int px = tid & 127;
  int ih = (tid >> 7) * 128;
  int r3 = rg * 4 + (px >> 5);
  int wc3 = px & 31;
  int hw3 = (bh * 32 + r3) * W_ + bw * 32 + wc3;
  float av[19];
#pragma unroll
  for (int k = 0; k < 19; k++) av[k] = aff[px * 20 + k];
  u16* ob = obuf + ((size_t)b * HW_ + hw3) * 256 + ih;
  for (int i0 = 0; i0 < 128; i0 += 16) {
    float o16[16];
#pragma unroll
    for (int j = 0; j < 16; j++) o16[j] = 0.f;
#pragma unroll
    for (int k = 0; k < 19; k++) {
      float a = av[k];
      const float* vr = &vall[k * 256 + ih + i0];
#pragma unroll
      for (int j = 0; j < 16; j++) o16[j] += a * vr[j];
    }
    uint4 w0, w1;
    w0.x = (u32)f2bf(o16[0]) | ((u32)f2bf(o16[1]) << 16);
    w0.y = (u32)f2bf(o16[2]) | ((u32)f2bf(o16[3]) << 16);
    w0.z = (u32)f2bf(o16[4]) | ((u32)f2bf(o16[5]) << 16);
    w0.w = (u32)f2bf(o16[6]) | ((u32)f2bf(o16[7]) << 16);
    w1.x = (u32)f2bf(o16[8]) | ((u32)f2bf(o16[9]) << 16);
    w1.y = (u32)f2bf(o16[10]) | ((u32)f2bf(o16[11]) << 16);
    w1.z = (u32)f2bf(o16[12]) | ((u32)f2bf(o16[13]) << 16);
    w1.w = (u32)f2bf(o16[14]) | ((u32)f2bf(o16[15]) << 16);
    *(uint4*)&ob[i0] = w0;
    *(uint4*)&ob[i0 + 8] = w1;
  }
}

// ---------------- final: BN (inline stats) + PReLU + residual; y read as bf16 ----------------
__global__ __launch_bounds__(256) void final_kernel(const float* __restrict__ x,
                                                    const u16* __restrict__ ybf,
                                                    const float* __restrict__ sums,
                                                    const float* __restrict__ sumsq,
                                                    const float* __restrict__ gamma,
                                                    const float* __restrict__ beta,
                                                    const float* __restrict__ oa,
                                                    float* __restrict__ out) {
  size_t base = (size_t)blockIdx.x * 4096 + threadIdx.x * 4;
  int c = (int)((base >> 13) & 511);
  const float inv_cnt = 1.f / 65536.f;
  float mu = sums[c] * inv_cnt;
  float var = sumsq[c] * inv_cnt - mu * mu;
  float iv = rsqrtf(var + 1e-5f);
  float sc = gamma[c] * iv;
  float sh = beta[c] - mu * sc;
  float a = oa[c];
#pragma unroll
  for (int jj = 0; jj < 4; jj++) {
    size_t idx = base + (size_t)jj * 1024;
    ushort4 yv = *(const ushort4*)&ybf[idx];
    float4 xv = *(const float4*)&x[idx];
    float4 r;
    float t;
    t = bf2f(yv.x) * sc + sh; r.x = xv.x + fmaxf(t, 0.f) + a * fminf(t, 0.f);
    t = bf2f(yv.y) * sc + sh; r.y = xv.y + fmaxf(t, 0.f) + a * fminf(t, 0.f);
    t = bf2f(yv.z) * sc + sh; r.z = xv.z + fmaxf(t, 0.f) + a * fminf(t, 0.f);
    t = bf2f(yv.w) * sc + sh; r.w = xv.w + fmaxf(t, 0.f) + a * fminf(t, 0.f);
    *(float4*)&out[idx] = r;
  }
}

extern "C" void kernel_launch(void* const* d_in, const int* in_sizes, int n_in,
                              void* d_out, int out_size, void* d_ws, size_t ws_size,
                              hipStream_t stream) {
  const float* x     = (const float*)d_in[0];
  const float* camw  = (const float*)d_in[1];
  const float* camb  = (const float*)d_in[2];
  const float* gw1   = (const float*)d_in[3];
  const float* ga    = (const float*)d_in[4];
  const float* gw2   = (const float*)d_in[5];
  const float* fw    = (const float*)d_in[6];
  const float* fb    = (const float*)d_in[7];
  const float* ra    = (const float*)d_in[8];
  const float* qw    = (const float*)d_in[9];
  const float* qb    = (const float*)d_in[10];
  const float* kw    = (const float*)d_in[11];
  const float* kb    = (const float*)d_in[12];
  const float* vw    = (const float*)d_in[13];
  const float* vb    = (const float*)d_in[14];
  const float* ow    = (const float*)d_in[15];
  const float* gamma = (const float*)d_in[16];
  const float* beta  = (const float*)d_in[17];
  const float* oa    = (const float*)d_in[18];
  float* out = (float*)d_out;
  float* ws = (float*)d_ws;

  // ---- workspace layout (float units) ----
  float* cam    = ws;                    // 1,245,184
  float* bconf  = cam + 1245184;         // 2,048 pad
  float* pconf  = bconf + 2048;          // 1,245,184
  float* locl   = pconf + 1245184;       // 622,592 (unused, layout kept)
  float* locl2f = locl + 622592;         // 1280*512 = 655,360
  float* keyo   = locl2f + 655360;       // 1280*256 = 327,680
  float* valo   = keyo + 327680;         // 38,912
  float* sums   = valo + 38912;          // 512
  float* sumsq  = sums + 512;            // 512
  float* scale  = sumsq + 512;           // 512 (unused)
  float* shift  = scale + 512;           // 512 (unused)
  u16* qwbf   = (u16*)(shift + 512);     // 131,072
  u16* owbf   = qwbf + 131072;           // 131,072
  u16* kwbf   = owbf + 131072;           // 131,072
  u16* gw2bf  = kwbf + 131072;           // 262,144
  u16* camwbf = gw2bf + 262144;          // 16,384 (32x512)
  u16* tbuf   = camwbf + 16384;          // 1280*512 = 655,360
  u16* l2bf   = tbuf + 655360;           // 1280*512 = 655,360
  u16* xt     = l2bf + 655360;           // 33,554,432 u16 (64 MB)
  u16* obuf   = xt;                      // overlay: all xt readers precede attn2
  u16* qbuf   = xt + 33554432;           // 16,777,216 u16 (32 MB)
  u16* ybf    = qbuf;                    // overlay: 33,554,432 u16 (64 MB), written after attn consumes qbuf
  float* part = (float*)(qbuf + 33554432); // 4*1216*512 floats = 10 MB (after ybf region)

  xpose_prep_kernel<<<8865, 256, 0, stream>>>(x, xt, qw, ow, kw, gw2, camw,
                                              qwbf, owbf, kwbf, gw2bf, camwbf,
                                              sums, (float*)(tbuf + 1216 * 512));
  gemm_cam_kernel<<<dim3(64, 8), 256, 0, stream>>>(xt, camwbf, camb, cam);
  softcls_kernel<<<1216, 256, 0, stream>>>(cam, bconf, pconf);
  local_part_q_kernel<<<768, 256, 0, stream>>>(xt, pconf, part, qwbf, qb, qbuf);
  t_q_kernel<<<560, 256, 0, stream>>>(part, bconf, gw1, ga, tbuf, xt, qwbf, qb, qbuf);
  small1_q_kernel<<<296, 256, 0, stream>>>(tbuf, gw2bf, locl2f, l2bf, xt, qwbf, qb, qbuf);
  small2gv_q_kernel<<<432, 256, 0, stream>>>(l2bf, kwbf, kb, keyo,
                                             locl2f, fw, fb, ra, vw, vb, valo,
                                             xt, qwbf, qb, qbuf);
  attn2_kernel<<<512, 256, 0, stream>>>(qbuf, keyo, valo, obuf);
  gemm_big_kernel<256, 512, true, false, true, true>
      <<<dim3(256, 8), 256, 0, stream>>>(obuf, owbf, nullptr, ybf, sums, sumsq);
  final_kernel<<<8192, 256, 0, stream>>>(x, ybf, sums, sumsq, gamma, beta, oa, out);
}